// Round 5
// baseline (133.371 us; speedup 1.0000x reference)
//
#include <hip/hip_runtime.h>
#include <math.h>

#define N_BOX 8192
#define NW 128              // 8192 / 64 words per keep-mask row
#define NTHR 512
#define LCAP 24576          // edges staged in LDS (96 KiB)
#define NRBLK 256           // rank blocks: 16 ech x 16 cch (512 rows x 512 cands)
#define NPTILE 576          // pair tiles: sum_w ceil((w+1)/16), 1024 rows x 64 cands
#define RPT 2               // rows per thread in pair role
#define WPB 8               // waves per block (512/64)
#define NWAVE (NPTILE * WPB)// 4608 pair waves
#define SLOT 128            // edge slots per wave
#define WSPT (NWAVE / NTHR) // 9 wave-counts per stageB thread
#define NCH 16              // candidate chunks for rank stage (512 each)
#define THR_C 0.7f
#define IOU_THR_C 0.5f
#define EPS_C 1e-9f

// SCALER = max(3508/1280, 2480/1280) computed in double then rounded to f32,
// matching numpy/jax float32 weak-typed scalar promotion.
__device__ __constant__ float kScaler = (float)(3508.0 / 1280.0);

// u64 key: ascending order == stable argsort(-masked_score). Unique (index in
// low bits). Invalid (-inf) keys sort strictly after all valid keys.
static __device__ __forceinline__ unsigned long long key_from(float c0, float c1, int i) {
    bool valid = (c0 > THR_C) || (c1 > THR_C);
    float ms = valid ? fmaxf(c0, c1) : -INFINITY;
    unsigned int u = __float_as_uint(ms);
    unsigned int m = (u & 0x80000000u) ? ~u : (u | 0x80000000u); // ascending map
    unsigned int d = ~m;                                          // descending key
    return ((unsigned long long)d << 32) | (unsigned int)i;
}

// ---------------------------------------------------------------------------
// Stage A (one launch, two block roles, no inter-stage dependency):
//  blocks [0, NRBLK): rank role (scheduled FIRST so they overlap pair work).
//    rank(i) = #{j : key_j < key_i} partial counts over one 512-cand chunk.
//  blocks [NRBLK, NRBLK+NPTILE): pair role, one tile each (perfect balance).
//    Tile pb -> (w, h) via closed form over groups g = w>>4 (ntiles(w) =
//    ceil((w+1)/16) = g+1, group base 8g(g+1)). Tile = rows [1024h,1024h+1023]
//    x candidate word w (64 boxes). For each pair i<j, both valid, IoU>thr:
//    emit ONE edge directed from the higher-priority (smaller-key) box.
//    Screen: iou>0.5 => inter > (ra+ca)/3 in real arithmetic; unclamped
//    iw*ih > 0.2ra+0.2ca is conservative (1.67x margin dwarfs fp error; the
//    iw<0&ih<0 false-positive case is clamped away in the exact path), so the
//    exact reference arithmetic runs only for gated pairs -> bit-identical
//    decisions. Edges go to the wave's private slot; wcnt is ALWAYS written
//    (no init; count > SLOT acts as fallback sentinel).
// ---------------------------------------------------------------------------
__global__ __launch_bounds__(NTHR) void stageA(const float* __restrict__ conf,
                                               const float* __restrict__ bboxes,
                                               int* __restrict__ partial,
                                               unsigned int* __restrict__ wcnt,
                                               unsigned int* __restrict__ wslot) {
    int b = blockIdx.x;
    int t = threadIdx.x;
    if (b < NRBLK) {
        // ---- rank role: 512 rows x 512 candidates ----
        __shared__ unsigned long long ck[512];           // 4 KiB candidate keys
        int ech = b >> 4;         // element chunk 0..15 (512 rows)
        int cch = b & 15;         // candidate chunk 0..15 (512 cands)
        {
            int j = (cch << 9) + t;
            float2 cc = ((const float2*)conf)[j];
            ck[t] = key_from(cc.x, cc.y, j);
        }
        __syncthreads();
        int i = (ech << 9) + t;
        float2 ci = ((const float2*)conf)[i];
        unsigned long long ki = key_from(ci.x, ci.y, i);
        const ulonglong2* ckp = (const ulonglong2*)ck;
        int a0 = 0, a1 = 0, a2 = 0, a3 = 0;
#pragma unroll 4
        for (int l = 0; l < 256; l += 2) {
            ulonglong2 u = ckp[l];
            ulonglong2 v = ckp[l + 1];
            a0 += (u.x < ki) ? 1 : 0;
            a1 += (u.y < ki) ? 1 : 0;
            a2 += (v.x < ki) ? 1 : 0;
            a3 += (v.y < ki) ? 1 : 0;
        }
        partial[cch * N_BOX + i] = (a0 + a1) + (a2 + a3);
    } else {
        // ---- pair role: one 1024-row x 64-cand tile ----
        int pb = b - NRBLK;                 // 0..575, block-uniform
        int g = 0;                          // group: w in [16g, 16g+15]
        while (8 * (g + 1) * (g + 2) <= pb) ++g;   // <=8 scalar iterations
        int off = pb - 8 * g * (g + 1);
        int wq = off / (g + 1);
        int w = (g << 4) + wq;              // j-word 0..127
        int h = off - wq * (g + 1);         // tile index 0..g
        int waveid = pb * WPB + (t >> 6);
        int lane = t & 63;
        __shared__ float4 cb[64];
        __shared__ float caF[64];
        __shared__ float ca02[64];
        __shared__ unsigned long long cbk[64];
        __shared__ unsigned long long jvS;
        if (t < 64) {                       // exactly wave 0
            int j = (w << 6) + t;
            float4 c = ((const float4*)bboxes)[j];
            cb[t] = c;
            float a = (c.z - c.x) * (c.w - c.y);
            caF[t] = a;
            ca02[t] = 0.2f * a;
            float2 cc = ((const float2*)conf)[j];
            cbk[t] = key_from(cc.x, cc.y, j);
            unsigned long long bv = __ballot((cc.x > THR_C) || (cc.y > THR_C));
            if (t == 0) jvS = bv;
        }
        __syncthreads();
        unsigned long long jv = jvS;
        int ibase = h << 10;                // h * 1024
        // 2 register-resident rows per thread (named, static indices)
        float4 rb0, rb1;
        float raF0, raF1, raS0, raS1;
        unsigned long long ki0, ki1, jm0, jm1;
        {
            int i = ibase + t;
            int rel = i - (w << 6);
            unsigned long long jm = jv;     // valid j AND j > i
            if (rel >= 63) jm = 0ull;
            else if (rel >= 0) jm &= ~((2ull << rel) - 1ull);
            float2 cc = ((const float2*)conf)[i];
            if (!((cc.x > THR_C) || (cc.y > THR_C))) jm = 0ull;
            jm0 = jm;
            rb0 = ((const float4*)bboxes)[i];
            raF0 = (rb0.z - rb0.x) * (rb0.w - rb0.y);
            raS0 = 0.2f * raF0;
            ki0 = key_from(cc.x, cc.y, i);
        }
        {
            int i = ibase + 512 + t;
            int rel = i - (w << 6);
            unsigned long long jm = jv;
            if (rel >= 63) jm = 0ull;
            else if (rel >= 0) jm &= ~((2ull << rel) - 1ull);
            float2 cc = ((const float2*)conf)[i];
            if (!((cc.x > THR_C) || (cc.y > THR_C))) jm = 0ull;
            jm1 = jm;
            rb1 = ((const float4*)bboxes)[i];
            raF1 = (rb1.z - rb1.x) * (rb1.w - rb1.y);
            raS1 = 0.2f * raF1;
            ki1 = key_from(cc.x, cc.y, i);
        }
        int wc = 0;                         // wave-uniform running edge count
        if (__any((jm0 | jm1) != 0ull)) {
            unsigned long long bits0 = 0ull, bits1 = 0ull;
            for (int bb = 0; bb < 64; ++bb) {
                float4 c = cb[bb];
                float s2 = ca02[bb];
                // row 0: 9-op screen (unclamped; conservative, see header)
                float iw0 = fminf(rb0.z, c.z) - fmaxf(rb0.x, c.x);
                float ih0 = fminf(rb0.w, c.w) - fmaxf(rb0.y, c.y);
                if (iw0 * ih0 > raS0 + s2) {
                    // exact reference arithmetic (bit-identical decision)
                    float iwc = fmaxf(iw0, 0.0f);
                    float ihc = fmaxf(ih0, 0.0f);
                    float inter = iwc * ihc;
                    float iou = inter / (raF0 + caF[bb] - inter + EPS_C);
                    if (iou > IOU_THR_C) bits0 |= (1ull << bb);
                }
                // row 1
                float iw1 = fminf(rb1.z, c.z) - fmaxf(rb1.x, c.x);
                float ih1 = fminf(rb1.w, c.w) - fmaxf(rb1.y, c.y);
                if (iw1 * ih1 > raS1 + s2) {
                    float iwc = fmaxf(iw1, 0.0f);
                    float ihc = fmaxf(ih1, 0.0f);
                    float inter = iwc * ihc;
                    float iou = inter / (raF1 + caF[bb] - inter + EPS_C);
                    if (iou > IOU_THR_C) bits1 |= (1ull << bb);
                }
            }
            // wave-local compaction into the wave's private slot (q = 0)
            {
                unsigned long long eb = bits0 & jm0;
                if (__any(eb != 0ull)) {
                    int ec = __popcll(eb);
                    int pre = ec;
#pragma unroll
                    for (int d = 1; d < 64; d <<= 1) {
                        int vv = __shfl_up(pre, d, 64);
                        if (lane >= d) pre += vv;
                    }
                    int tot = __shfl(pre, 63, 64);
                    int idx = wc + pre - ec;
                    unsigned long long tb = eb;
                    int i = ibase + t;
                    while (tb) {
                        int bb = __builtin_ctzll(tb); tb &= tb - 1;
                        if (idx < SLOT) {
                            int j = (w << 6) + bb;
                            // smaller key = higher priority = suppressor
                            unsigned int e = (ki0 < cbk[bb])
                                             ? (((unsigned int)i << 13) | (unsigned int)j)
                                             : (((unsigned int)j << 13) | (unsigned int)i);
                            wslot[(size_t)waveid * SLOT + idx] = e;
                        }
                        ++idx;
                    }
                    wc += tot;
                }
            }
            // q = 1
            {
                unsigned long long eb = bits1 & jm1;
                if (__any(eb != 0ull)) {
                    int ec = __popcll(eb);
                    int pre = ec;
#pragma unroll
                    for (int d = 1; d < 64; d <<= 1) {
                        int vv = __shfl_up(pre, d, 64);
                        if (lane >= d) pre += vv;
                    }
                    int tot = __shfl(pre, 63, 64);
                    int idx = wc + pre - ec;
                    unsigned long long tb = eb;
                    int i = ibase + 512 + t;
                    while (tb) {
                        int bb = __builtin_ctzll(tb); tb &= tb - 1;
                        if (idx < SLOT) {
                            int j = (w << 6) + bb;
                            unsigned int e = (ki1 < cbk[bb])
                                             ? (((unsigned int)i << 13) | (unsigned int)j)
                                             : (((unsigned int)j << 13) | (unsigned int)i);
                            wslot[(size_t)waveid * SLOT + idx] = e;
                        }
                        ++idx;
                    }
                    wc += tot;
                }
            }
        }
        if (lane == 0) wcnt[waveid] = (unsigned int)wc;  // >SLOT => sentinel
    }
}

// ---------------------------------------------------------------------------
// Stage B (single block): valid mask -> prefix-sum wave counts -> gather
// edges to LDS -> Jacobi-iterated greedy fixpoint (verified logic; k_new ==
// k_old certifies exact greedy) -> rank-sum -> scattered (N,6) output.
// Fallback (any wcnt>SLOT or total>LCAP; never on this data): exact serial
// greedy over rank order via inverse permutation, IoU recomputed on the fly.
// ---------------------------------------------------------------------------
__global__ __launch_bounds__(NTHR) void stageB(const float* __restrict__ conf,
                                               const float* __restrict__ bboxes,
                                               const int* __restrict__ partial,
                                               const unsigned int* __restrict__ wcnt,
                                               const unsigned int* __restrict__ wslot,
                                               float* __restrict__ out) {
    __shared__ unsigned int eL[LCAP];                       // 96 KiB
    __shared__ unsigned long long kL[NW], tL[NW], vL[NW];   // 3 KiB
    __shared__ int wsum[NTHR];                              // 2 KiB
    __shared__ int chg[3];
    __shared__ int fbF, nvF;
    int t = threadIdx.x;
    if (t == 0) { fbF = 0; nvF = 0; chg[0] = 0; chg[1] = 0; chg[2] = 0; }
    // valid mask (original index space), coalesced + ballot
    for (int base = 0; base < N_BOX; base += NTHR) {
        int i = base + t;
        float2 cc = ((const float2*)conf)[i];
        unsigned long long bv = __ballot((cc.x > THR_C) || (cc.y > THR_C));
        if ((t & 63) == 0) vL[i >> 6] = bv;
    }
    // per-thread wave-count partial sums
    int nq[WSPT], myo[WSPT];
    int s = 0;
    bool ov = false;
#pragma unroll
    for (int q = 0; q < WSPT; ++q) {
        int v = (int)wcnt[t * WSPT + q];
        nq[q] = v; myo[q] = s; s += v;
        if (v > SLOT) ov = true;
    }
    wsum[t] = s;
    __syncthreads();                       // vL, wsum, shared init done
    if (t < NW) kL[t] = vL[t];             // main-path keep init
    // Hillis-Steele inclusive scan over 512 partial sums
    for (int off = 1; off < NTHR; off <<= 1) {
        int v = (t >= off) ? wsum[t - off] : 0;
        __syncthreads();
        wsum[t] += v;
        __syncthreads();
    }
    int ebase = wsum[t] - s;               // exclusive base for this thread
    int totE = wsum[NTHR - 1];
    if (ov || totE > LCAP) fbF = 1;        // benign same-value race
    __syncthreads();
    int fb = fbF;
    if (!fb) {
        // gather this thread's 9 waves' edges into contiguous LDS
#pragma unroll
        for (int q = 0; q < WSPT; ++q) {
            int w2 = t * WSPT + q;
            int off = ebase + myo[q];
            for (int k = 0; k < nq[q]; ++k)
                eL[off + k] = wslot[(size_t)w2 * SLOT + k];
        }
    }
    __syncthreads();
    if (!fb) {
        for (int it = 0; it < N_BOX; ++it) {
            if (t < NW) tL[t] = 0ull;
            __syncthreads();
            for (int e = t; e < totE; e += NTHR) {
                unsigned int ed = eL[e];
                int src = (int)(ed >> 13);
                if ((kL[src >> 6] >> (src & 63)) & 1ull) {
                    int tg = (int)(ed & 8191u);
                    atomicOr(&tL[tg >> 6], 1ull << (tg & 63));
                }
            }
            __syncthreads();
            if (t < NW) {
                unsigned long long nk = vL[t] & ~tL[t];
                if (nk != kL[t]) chg[it % 3] = 1;
                kL[t] = nk;
            }
            if (t == 0) chg[(it + 2) % 3] = 0;   // reset 2 barriers before reuse
            __syncthreads();
            if (chg[it % 3] == 0) break;         // uniform: read after barrier
        }
    } else {
        // fallback: build inverse permutation sinv[rank]=orig in eL, serial
        // greedy over rank order (one wave), then map kept ranks -> orig bits
        unsigned int* sinv = eL;
        for (int base = 0; base < N_BOX; base += NTHR) {
            int i = base + t;
            int r = 0;
#pragma unroll
            for (int c = 0; c < NCH; ++c) r += partial[c * N_BOX + i];
            sinv[r] = (unsigned int)i;
        }
        if (t < NW) { atomicAdd(&nvF, __popcll(vL[t])); tL[t] = 0ull; kL[t] = 0ull; }
        __syncthreads();
        int nv = nvF;
        if (t < 64) {
            for (int a = 0; a < nv - 1; ++a) {
                bool rem = (tL[a >> 6] >> (a & 63)) & 1ull;
                if (!rem) {
                    float4 r = ((const float4*)bboxes)[sinv[a]];
                    float ra = (r.z - r.x) * (r.w - r.y);
                    for (int b2 = a + 1 + t; b2 < nv; b2 += 64) {
                        float4 c = ((const float4*)bboxes)[sinv[b2]];
                        float ca = (c.z - c.x) * (c.w - c.y);
                        float iw = fminf(r.z, c.z) - fmaxf(r.x, c.x);
                        float ih = fminf(r.w, c.w) - fmaxf(r.y, c.y);
                        iw = fmaxf(iw, 0.0f);
                        ih = fmaxf(ih, 0.0f);
                        float inter = iw * ih;
                        float iou = inter / (ra + ca - inter + EPS_C);
                        if (iou > IOU_THR_C) atomicOr(&tL[b2 >> 6], 1ull << (b2 & 63));
                    }
                }
            }
        }
        __syncthreads();
        for (int a = t; a < nv; a += NTHR) {
            if (!((tL[a >> 6] >> (a & 63)) & 1ull)) {
                int ia = (int)sinv[a];
                atomicOr(&kL[ia >> 6], 1ull << (ia & 63));
            }
        }
    }
    __syncthreads();
    // output: row rank(i) <- kept ? [bbox_i*SCALER, conf_i] : zeros.
    // rank is a bijection, so every output row is written exactly once.
    // Suppressed/invalid rows are exactly 0.0 in the reference (positive
    // values * 0.0), so literal zeros are bit-identical.
    for (int base = 0; base < N_BOX; base += NTHR) {
        int i = base + t;
        int r = 0;
#pragma unroll
        for (int c = 0; c < NCH; ++c) r += partial[c * N_BOX + i];
        bool kept = (kL[i >> 6] >> (i & 63)) & 1ull;
        if (kept) {
            float4 bx = ((const float4*)bboxes)[i];
            float2 cc = ((const float2*)conf)[i];
            out[r * 6 + 0] = bx.x * kScaler;
            out[r * 6 + 1] = bx.y * kScaler;
            out[r * 6 + 2] = bx.z * kScaler;
            out[r * 6 + 3] = bx.w * kScaler;
            out[r * 6 + 4] = cc.x;
            out[r * 6 + 5] = cc.y;
        } else {
            out[r * 6 + 0] = 0.0f;
            out[r * 6 + 1] = 0.0f;
            out[r * 6 + 2] = 0.0f;
            out[r * 6 + 3] = 0.0f;
            out[r * 6 + 4] = 0.0f;
            out[r * 6 + 5] = 0.0f;
        }
    }
}

extern "C" void kernel_launch(void* const* d_in, const int* in_sizes, int n_in,
                              void* d_out, int out_size, void* d_ws, size_t ws_size,
                              hipStream_t stream) {
    const float* cls_conf = (const float*)d_in[0];   // (8192, 2)
    const float* bboxes   = (const float*)d_in[1];   // (8192, 4)
    float* out = (float*)d_out;                      // (8192, 6)

    char* ws = (char*)d_ws;
    int*          partial = (int*)(ws + 0);                    // 512 KiB (16 chunks)
    unsigned int* wcnt    = (unsigned int*)(ws + 524288);      //  18 KiB (4608)
    unsigned int* wslot   = (unsigned int*)(ws + 557056);      // 2.25 MiB (4608*128)
    (void)ws_size; (void)in_sizes; (void)n_in; (void)out_size;

    stageA<<<NRBLK + NPTILE, NTHR, 0, stream>>>(cls_conf, bboxes, partial, wcnt, wslot);
    stageB<<<1, NTHR, 0, stream>>>(cls_conf, bboxes, partial, wcnt, wslot, out);
}

// Round 6
// 102.630 us; speedup vs baseline: 1.2995x; 1.2995x over previous
//
#include <hip/hip_runtime.h>
#include <math.h>

#define N_BOX 8192
#define NW 128              // 8192 / 64 words per keep-mask row
#define NTHR 512
#define LCAP 24576          // edges staged in LDS (96 KiB)
#define NRBLK 256           // rank blocks: 16 ech x 16 cch (512 rows x 512 cands)
#define NPTILE 576          // pair tiles: sum_w ceil((w+1)/16), 1024 rows x 64 cands
#define WPB 8               // waves per block (512/64)
#define NWAVE (NPTILE * WPB)// 4608 pair waves
#define SLOT 128            // edge slots per wave
#define WSPT (NWAVE / NTHR) // 9 wave-counts per stageB thread
#define NCH 16              // candidate chunks for rank stage (512 each)
#define THR_C 0.7f
#define IOU_THR_C 0.5f
#define EPS_C 1e-9f

// SCALER = max(3508/1280, 2480/1280) computed in double then rounded to f32,
// matching numpy/jax float32 weak-typed scalar promotion.
__device__ __constant__ float kScaler = (float)(3508.0 / 1280.0);

// u64 key: ascending order == stable argsort(-masked_score). Unique (index in
// low bits). Invalid (-inf) keys sort strictly after all valid keys.
static __device__ __forceinline__ unsigned long long key_from(float c0, float c1, int i) {
    bool valid = (c0 > THR_C) || (c1 > THR_C);
    float ms = valid ? fmaxf(c0, c1) : -INFINITY;
    unsigned int u = __float_as_uint(ms);
    unsigned int m = (u & 0x80000000u) ? ~u : (u | 0x80000000u); // ascending map
    unsigned int d = ~m;                                          // descending key
    return ((unsigned long long)d << 32) | (unsigned int)i;
}

// ---------------------------------------------------------------------------
// Stage A (one launch, two block roles, no inter-stage dependency):
//  blocks [0, NRBLK): rank role (scheduled FIRST so they overlap pair work).
//    rank(i) = #{j : key_j < key_i} partial counts over one 512-cand chunk.
//  blocks [NRBLK, NRBLK+NPTILE): pair role, one tile each (perfect balance).
//    Tile pb -> (w, h) via closed form over groups g = w>>4 (ntiles(w) =
//    ceil((w+1)/16) = g+1, group base 8g(g+1)). Tile = rows [1024h,1024h+1023]
//    x candidate word w. Wave 0 COMPACTS the valid candidates (~half) into
//    the LDS tile; the per-row constraint {j valid, j > i} becomes compacted
//    slots k >= kmin(i) = popcount(jv & bits<=rel). For each surviving pair:
//    CLAMPED screen inter > 0.2ra+0.2ca (iou>0.5 => inter > (ra+ca)/3 in real
//    arithmetic; 1.67x margin dwarfs fp error, and disjoint pairs give
//    inter==0 -> rejected), so the exact reference division runs only for
//    gated pairs -> bit-identical decisions. Edge directed from the
//    higher-priority (smaller-key) box, appended to the wave's private slot;
//    wcnt is ALWAYS written (no init; count > SLOT acts as fallback sentinel).
// ---------------------------------------------------------------------------
__global__ __launch_bounds__(NTHR) void stageA(const float* __restrict__ conf,
                                               const float* __restrict__ bboxes,
                                               int* __restrict__ partial,
                                               unsigned int* __restrict__ wcnt,
                                               unsigned int* __restrict__ wslot) {
    int b = blockIdx.x;
    int t = threadIdx.x;
    if (b < NRBLK) {
        // ---- rank role: 512 rows x 512 candidates ----
        __shared__ unsigned long long ck[512];           // 4 KiB candidate keys
        int ech = b >> 4;         // element chunk 0..15 (512 rows)
        int cch = b & 15;         // candidate chunk 0..15 (512 cands)
        {
            int j = (cch << 9) + t;
            float2 cc = ((const float2*)conf)[j];
            ck[t] = key_from(cc.x, cc.y, j);
        }
        __syncthreads();
        int i = (ech << 9) + t;
        float2 ci = ((const float2*)conf)[i];
        unsigned long long ki = key_from(ci.x, ci.y, i);
        const ulonglong2* ckp = (const ulonglong2*)ck;
        int a0 = 0, a1 = 0, a2 = 0, a3 = 0;
#pragma unroll 4
        for (int l = 0; l < 256; l += 2) {
            ulonglong2 u = ckp[l];
            ulonglong2 v = ckp[l + 1];
            a0 += (u.x < ki) ? 1 : 0;
            a1 += (u.y < ki) ? 1 : 0;
            a2 += (v.x < ki) ? 1 : 0;
            a3 += (v.y < ki) ? 1 : 0;
        }
        partial[cch * N_BOX + i] = (a0 + a1) + (a2 + a3);
    } else {
        // ---- pair role: one 1024-row x (compacted) 64-cand tile ----
        int pb = b - NRBLK;                 // 0..575, block-uniform
        int g = 0;                          // group: w in [16g, 16g+15]
        while (8 * (g + 1) * (g + 2) <= pb) ++g;   // <=8 scalar iterations
        int off = pb - 8 * g * (g + 1);
        int wq = off / (g + 1);
        int w = (g << 4) + wq;              // j-word 0..127
        int h = off - wq * (g + 1);         // tile index 0..g
        int waveid = pb * WPB + (t >> 6);
        int lane = t & 63;
        __shared__ float4 cb[64];           // compacted valid candidates
        __shared__ float ca02[64];          // 0.2*area (screen threshold part)
        __shared__ unsigned long long cbk[64];
        __shared__ unsigned char cjr[64];   // rel index (0..63) of slot
        __shared__ unsigned long long jvS;
        __shared__ int nvjS;
        if (t < 64) {                       // exactly wave 0
            int j = (w << 6) + t;
            float2 cc = ((const float2*)conf)[j];
            bool v = (cc.x > THR_C) || (cc.y > THR_C);
            unsigned long long bv = __ballot(v);
            if (v) {
                int pos = __popcll(bv & ((1ull << t) - 1ull));
                float4 c = ((const float4*)bboxes)[j];
                cb[pos] = c;
                ca02[pos] = 0.2f * ((c.z - c.x) * (c.w - c.y));
                cbk[pos] = key_from(cc.x, cc.y, j);
                cjr[pos] = (unsigned char)t;
            }
            if (t == 0) { jvS = bv; nvjS = __popcll(bv); }
        }
        __syncthreads();
        unsigned long long jv = jvS;
        int nvj = nvjS;
        int ibase = h << 10;                // h * 1024
        // 2 register-resident rows per thread (named, static indices)
        float4 rb0, rb1;
        float raF0, raF1, raS0, raS1;
        unsigned long long ki0, ki1;
        int km0, km1;                       // first allowed compacted slot (64=none)
        {
            int i = ibase + t;
            int rel = i - (w << 6);
            float2 cc = ((const float2*)conf)[i];
            bool iv = (cc.x > THR_C) || (cc.y > THR_C);
            if (!iv || rel >= 63)      km0 = 64;
            else if (rel >= 0)         km0 = __popcll(jv & ((2ull << rel) - 1ull));
            else                       km0 = 0;
            rb0 = ((const float4*)bboxes)[i];
            raF0 = (rb0.z - rb0.x) * (rb0.w - rb0.y);
            raS0 = 0.2f * raF0;
            ki0 = key_from(cc.x, cc.y, i);
        }
        {
            int i = ibase + 512 + t;
            int rel = i - (w << 6);
            float2 cc = ((const float2*)conf)[i];
            bool iv = (cc.x > THR_C) || (cc.y > THR_C);
            if (!iv || rel >= 63)      km1 = 64;
            else if (rel >= 0)         km1 = __popcll(jv & ((2ull << rel) - 1ull));
            else                       km1 = 0;
            rb1 = ((const float4*)bboxes)[i];
            raF1 = (rb1.z - rb1.x) * (rb1.w - rb1.y);
            raS1 = 0.2f * raF1;
            ki1 = key_from(cc.x, cc.y, i);
        }
        int wc = 0;                         // wave-uniform running edge count
        if (__any((km0 < nvj) || (km1 < nvj))) {
            unsigned long long bits0 = 0ull, bits1 = 0ull;
            for (int bb = 0; bb < nvj; ++bb) {
                float4 c = cb[bb];
                float s2 = ca02[bb];
                // row 0: clamped screen (disjoint pairs -> inter 0 -> reject)
                float iw0 = fminf(rb0.z, c.z) - fmaxf(rb0.x, c.x);
                float ih0 = fminf(rb0.w, c.w) - fmaxf(rb0.y, c.y);
                float inter0 = fmaxf(iw0, 0.0f) * fmaxf(ih0, 0.0f);
                if (inter0 > raS0 + s2) {
                    // exact reference arithmetic (bit-identical decision)
                    float caF = (c.z - c.x) * (c.w - c.y);
                    float iou = inter0 / (raF0 + caF - inter0 + EPS_C);
                    if (iou > IOU_THR_C) bits0 |= (1ull << bb);
                }
                // row 1
                float iw1 = fminf(rb1.z, c.z) - fmaxf(rb1.x, c.x);
                float ih1 = fminf(rb1.w, c.w) - fmaxf(rb1.y, c.y);
                float inter1 = fmaxf(iw1, 0.0f) * fmaxf(ih1, 0.0f);
                if (inter1 > raS1 + s2) {
                    float caF = (c.z - c.x) * (c.w - c.y);
                    float iou = inter1 / (raF1 + caF - inter1 + EPS_C);
                    if (iou > IOU_THR_C) bits1 |= (1ull << bb);
                }
            }
            // wave-local compaction into the wave's private slot (row 0)
            {
                unsigned long long m = (km0 >= 64) ? 0ull : (~0ull << km0);
                unsigned long long eb = bits0 & m;
                if (__any(eb != 0ull)) {
                    int ec = __popcll(eb);
                    int pre = ec;
#pragma unroll
                    for (int d = 1; d < 64; d <<= 1) {
                        int vv = __shfl_up(pre, d, 64);
                        if (lane >= d) pre += vv;
                    }
                    int tot = __shfl(pre, 63, 64);
                    int idx = wc + pre - ec;
                    unsigned long long tb = eb;
                    int i = ibase + t;
                    while (tb) {
                        int bb = __builtin_ctzll(tb); tb &= tb - 1;
                        if (idx < SLOT) {
                            int j = (w << 6) + (int)cjr[bb];
                            // smaller key = higher priority = suppressor
                            unsigned int e = (ki0 < cbk[bb])
                                             ? (((unsigned int)i << 13) | (unsigned int)j)
                                             : (((unsigned int)j << 13) | (unsigned int)i);
                            wslot[(size_t)waveid * SLOT + idx] = e;
                        }
                        ++idx;
                    }
                    wc += tot;
                }
            }
            // row 1
            {
                unsigned long long m = (km1 >= 64) ? 0ull : (~0ull << km1);
                unsigned long long eb = bits1 & m;
                if (__any(eb != 0ull)) {
                    int ec = __popcll(eb);
                    int pre = ec;
#pragma unroll
                    for (int d = 1; d < 64; d <<= 1) {
                        int vv = __shfl_up(pre, d, 64);
                        if (lane >= d) pre += vv;
                    }
                    int tot = __shfl(pre, 63, 64);
                    int idx = wc + pre - ec;
                    unsigned long long tb = eb;
                    int i = ibase + 512 + t;
                    while (tb) {
                        int bb = __builtin_ctzll(tb); tb &= tb - 1;
                        if (idx < SLOT) {
                            int j = (w << 6) + (int)cjr[bb];
                            unsigned int e = (ki1 < cbk[bb])
                                             ? (((unsigned int)i << 13) | (unsigned int)j)
                                             : (((unsigned int)j << 13) | (unsigned int)i);
                            wslot[(size_t)waveid * SLOT + idx] = e;
                        }
                        ++idx;
                    }
                    wc += tot;
                }
            }
        }
        if (lane == 0) wcnt[waveid] = (unsigned int)wc;  // >SLOT => sentinel
    }
}

// ---------------------------------------------------------------------------
// Stage B (single block): valid mask -> prefix-sum wave counts -> gather
// edges to LDS -> Jacobi-iterated greedy fixpoint (verified logic; k_new ==
// k_old certifies exact greedy) -> rank-sum -> scattered (N,6) output.
// Fallback (any wcnt>SLOT or total>LCAP; never on this data): exact serial
// greedy over rank order via inverse permutation, IoU recomputed on the fly.
// ---------------------------------------------------------------------------
__global__ __launch_bounds__(NTHR) void stageB(const float* __restrict__ conf,
                                               const float* __restrict__ bboxes,
                                               const int* __restrict__ partial,
                                               const unsigned int* __restrict__ wcnt,
                                               const unsigned int* __restrict__ wslot,
                                               float* __restrict__ out) {
    __shared__ unsigned int eL[LCAP];                       // 96 KiB
    __shared__ unsigned long long kL[NW], tL[NW], vL[NW];   // 3 KiB
    __shared__ int wsum[NTHR];                              // 2 KiB
    __shared__ int chg[3];
    __shared__ int fbF, nvF;
    int t = threadIdx.x;
    if (t == 0) { fbF = 0; nvF = 0; chg[0] = 0; chg[1] = 0; chg[2] = 0; }
    // valid mask (original index space), coalesced + ballot
    for (int base = 0; base < N_BOX; base += NTHR) {
        int i = base + t;
        float2 cc = ((const float2*)conf)[i];
        unsigned long long bv = __ballot((cc.x > THR_C) || (cc.y > THR_C));
        if ((t & 63) == 0) vL[i >> 6] = bv;
    }
    // per-thread wave-count partial sums
    int nq[WSPT], myo[WSPT];
    int s = 0;
    bool ov = false;
#pragma unroll
    for (int q = 0; q < WSPT; ++q) {
        int v = (int)wcnt[t * WSPT + q];
        nq[q] = v; myo[q] = s; s += v;
        if (v > SLOT) ov = true;
    }
    wsum[t] = s;
    __syncthreads();                       // vL, wsum, shared init done
    if (t < NW) kL[t] = vL[t];             // main-path keep init
    // Hillis-Steele inclusive scan over 512 partial sums
    for (int off = 1; off < NTHR; off <<= 1) {
        int v = (t >= off) ? wsum[t - off] : 0;
        __syncthreads();
        wsum[t] += v;
        __syncthreads();
    }
    int ebase = wsum[t] - s;               // exclusive base for this thread
    int totE = wsum[NTHR - 1];
    if (ov || totE > LCAP) fbF = 1;        // benign same-value race
    __syncthreads();
    int fb = fbF;
    if (!fb) {
        // gather this thread's 9 waves' edges into contiguous LDS
#pragma unroll
        for (int q = 0; q < WSPT; ++q) {
            int w2 = t * WSPT + q;
            int off = ebase + myo[q];
            for (int k = 0; k < nq[q]; ++k)
                eL[off + k] = wslot[(size_t)w2 * SLOT + k];
        }
    }
    __syncthreads();
    if (!fb) {
        for (int it = 0; it < N_BOX; ++it) {
            if (t < NW) tL[t] = 0ull;
            __syncthreads();
            for (int e = t; e < totE; e += NTHR) {
                unsigned int ed = eL[e];
                int src = (int)(ed >> 13);
                if ((kL[src >> 6] >> (src & 63)) & 1ull) {
                    int tg = (int)(ed & 8191u);
                    atomicOr(&tL[tg >> 6], 1ull << (tg & 63));
                }
            }
            __syncthreads();
            if (t < NW) {
                unsigned long long nk = vL[t] & ~tL[t];
                if (nk != kL[t]) chg[it % 3] = 1;
                kL[t] = nk;
            }
            if (t == 0) chg[(it + 2) % 3] = 0;   // reset 2 barriers before reuse
            __syncthreads();
            if (chg[it % 3] == 0) break;         // uniform: read after barrier
        }
    } else {
        // fallback: build inverse permutation sinv[rank]=orig in eL, serial
        // greedy over rank order (one wave), then map kept ranks -> orig bits
        unsigned int* sinv = eL;
        for (int base = 0; base < N_BOX; base += NTHR) {
            int i = base + t;
            int r = 0;
#pragma unroll
            for (int c = 0; c < NCH; ++c) r += partial[c * N_BOX + i];
            sinv[r] = (unsigned int)i;
        }
        if (t < NW) { atomicAdd(&nvF, __popcll(vL[t])); tL[t] = 0ull; kL[t] = 0ull; }
        __syncthreads();
        int nv = nvF;
        if (t < 64) {
            for (int a = 0; a < nv - 1; ++a) {
                bool rem = (tL[a >> 6] >> (a & 63)) & 1ull;
                if (!rem) {
                    float4 r = ((const float4*)bboxes)[sinv[a]];
                    float ra = (r.z - r.x) * (r.w - r.y);
                    for (int b2 = a + 1 + t; b2 < nv; b2 += 64) {
                        float4 c = ((const float4*)bboxes)[sinv[b2]];
                        float ca = (c.z - c.x) * (c.w - c.y);
                        float iw = fminf(r.z, c.z) - fmaxf(r.x, c.x);
                        float ih = fminf(r.w, c.w) - fmaxf(r.y, c.y);
                        iw = fmaxf(iw, 0.0f);
                        ih = fmaxf(ih, 0.0f);
                        float inter = iw * ih;
                        float iou = inter / (ra + ca - inter + EPS_C);
                        if (iou > IOU_THR_C) atomicOr(&tL[b2 >> 6], 1ull << (b2 & 63));
                    }
                }
            }
        }
        __syncthreads();
        for (int a = t; a < nv; a += NTHR) {
            if (!((tL[a >> 6] >> (a & 63)) & 1ull)) {
                int ia = (int)sinv[a];
                atomicOr(&kL[ia >> 6], 1ull << (ia & 63));
            }
        }
    }
    __syncthreads();
    // output: row rank(i) <- kept ? [bbox_i*SCALER, conf_i] : zeros.
    // rank is a bijection, so every output row is written exactly once.
    // Suppressed/invalid rows are exactly 0.0 in the reference (positive
    // values * 0.0), so literal zeros are bit-identical.
    for (int base = 0; base < N_BOX; base += NTHR) {
        int i = base + t;
        int r = 0;
#pragma unroll
        for (int c = 0; c < NCH; ++c) r += partial[c * N_BOX + i];
        bool kept = (kL[i >> 6] >> (i & 63)) & 1ull;
        if (kept) {
            float4 bx = ((const float4*)bboxes)[i];
            float2 cc = ((const float2*)conf)[i];
            out[r * 6 + 0] = bx.x * kScaler;
            out[r * 6 + 1] = bx.y * kScaler;
            out[r * 6 + 2] = bx.z * kScaler;
            out[r * 6 + 3] = bx.w * kScaler;
            out[r * 6 + 4] = cc.x;
            out[r * 6 + 5] = cc.y;
        } else {
            out[r * 6 + 0] = 0.0f;
            out[r * 6 + 1] = 0.0f;
            out[r * 6 + 2] = 0.0f;
            out[r * 6 + 3] = 0.0f;
            out[r * 6 + 4] = 0.0f;
            out[r * 6 + 5] = 0.0f;
        }
    }
}

extern "C" void kernel_launch(void* const* d_in, const int* in_sizes, int n_in,
                              void* d_out, int out_size, void* d_ws, size_t ws_size,
                              hipStream_t stream) {
    const float* cls_conf = (const float*)d_in[0];   // (8192, 2)
    const float* bboxes   = (const float*)d_in[1];   // (8192, 4)
    float* out = (float*)d_out;                      // (8192, 6)

    char* ws = (char*)d_ws;
    int*          partial = (int*)(ws + 0);                    // 512 KiB (16 chunks)
    unsigned int* wcnt    = (unsigned int*)(ws + 524288);      //  18 KiB (4608)
    unsigned int* wslot   = (unsigned int*)(ws + 557056);      // 2.25 MiB (4608*128)
    (void)ws_size; (void)in_sizes; (void)n_in; (void)out_size;

    stageA<<<NRBLK + NPTILE, NTHR, 0, stream>>>(cls_conf, bboxes, partial, wcnt, wslot);
    stageB<<<1, NTHR, 0, stream>>>(cls_conf, bboxes, partial, wcnt, wslot, out);
}

// Round 7
// 100.107 us; speedup vs baseline: 1.3323x; 1.0252x over previous
//
#include <hip/hip_runtime.h>
#include <math.h>

#define N_BOX 8192
#define NW 128              // 8192 / 64 words per keep-mask row
#define NTHR 512
#define LCAP 24576          // edges staged in LDS (96 KiB)
#define NRBLK 128           // rank blocks: 16 ech x 8 cch (512 rows x 1024 cands)
#define NPTILE 576          // pair tiles: sum_w ceil((w+1)/16), 1024 rows x 64 cands
#define WPB 8               // waves per block (512/64)
#define NWAVE (NPTILE * WPB)// 4608 pair waves
#define SLOT 128            // edge slots per wave
#define WSPT (NWAVE / NTHR) // 9 wave-counts per stageB thread
#define NCH 8               // candidate chunks for rank stage (1024 each)
#define THR_C 0.7f
#define IOU_THR_C 0.5f
#define EPS_C 1e-9f

// SCALER = max(3508/1280, 2480/1280) computed in double then rounded to f32,
// matching numpy/jax float32 weak-typed scalar promotion.
__device__ __constant__ float kScaler = (float)(3508.0 / 1280.0);

// u64 key: ascending order == stable argsort(-masked_score). Unique (index in
// low bits). Invalid (-inf) keys sort strictly after all valid keys.
static __device__ __forceinline__ unsigned long long key_from(float c0, float c1, int i) {
    bool valid = (c0 > THR_C) || (c1 > THR_C);
    float ms = valid ? fmaxf(c0, c1) : -INFINITY;
    unsigned int u = __float_as_uint(ms);
    unsigned int m = (u & 0x80000000u) ? ~u : (u | 0x80000000u); // ascending map
    unsigned int d = ~m;                                          // descending key
    return ((unsigned long long)d << 32) | (unsigned int)i;
}

// ---------------------------------------------------------------------------
// Stage A (one launch, two block roles, no inter-stage dependency):
//  blocks [0, NRBLK): rank role. rank(i) = #{j : key_j < key_i} partial
//    counts over one 1024-cand chunk (LDS broadcast reads), written
//    TRANSPOSED: partial[i*NCH + cch] so stageB reads 32 B/row contiguous.
//    cch==0 blocks also ballot-write validw (original index space).
//  blocks [NRBLK, NRBLK+NPTILE): pair role, one tile each (perfect balance).
//    Tile pb -> (w, h) closed form over groups g = w>>4 (ntiles(w) = g+1,
//    group base 8g(g+1)). Tile = rows [1024h, 1024h+1023] x candidate word w.
//    Wave 0 COMPACTS valid candidates into LDS; per-row constraint
//    {j valid, j > i} becomes compacted slots k >= kmin(i). CLAMPED screen
//    inter > 0.2ra+0.2ca (iou>0.5 => inter > (ra+ca)/3 in real arithmetic;
//    1.67x margin dwarfs fp error; disjoint pairs give inter==0 -> rejected),
//    so the exact reference division runs only for gated pairs ->
//    bit-identical decisions. Edge directed from the smaller-key box,
//    appended to the wave's private slot; wcnt ALWAYS written (no init;
//    count > SLOT acts as fallback sentinel).
// ---------------------------------------------------------------------------
__global__ __launch_bounds__(NTHR) void stageA(const float* __restrict__ conf,
                                               const float* __restrict__ bboxes,
                                               int* __restrict__ partial,
                                               unsigned long long* __restrict__ validw,
                                               unsigned int* __restrict__ wcnt,
                                               unsigned int* __restrict__ wslot) {
    int b = blockIdx.x;
    int t = threadIdx.x;
    if (b < NRBLK) {
        // ---- rank role: 512 rows x 1024 candidates ----
        __shared__ unsigned long long ck[1024];          // 8 KiB candidate keys
        int ech = b >> 3;         // element chunk 0..15 (512 rows)
        int cch = b & 7;          // candidate chunk 0..7 (1024 cands)
        for (int l = t; l < 1024; l += NTHR) {
            int j = (cch << 10) + l;
            float2 cc = ((const float2*)conf)[j];
            ck[l] = key_from(cc.x, cc.y, j);
        }
        __syncthreads();
        int i = (ech << 9) + t;
        float2 ci = ((const float2*)conf)[i];
        bool iv = (ci.x > THR_C) || (ci.y > THR_C);
        if (cch == 0) {          // valid mask for stageB (original index space)
            unsigned long long bv = __ballot(iv);
            if ((t & 63) == 0) validw[i >> 6] = bv;
        }
        unsigned long long ki = key_from(ci.x, ci.y, i);
        const ulonglong2* ckp = (const ulonglong2*)ck;
        int a0 = 0, a1 = 0, a2 = 0, a3 = 0;
#pragma unroll 4
        for (int l = 0; l < 512; l += 2) {
            ulonglong2 u = ckp[l];
            ulonglong2 v = ckp[l + 1];
            a0 += (u.x < ki) ? 1 : 0;
            a1 += (u.y < ki) ? 1 : 0;
            a2 += (v.x < ki) ? 1 : 0;
            a3 += (v.y < ki) ? 1 : 0;
        }
        partial[i * NCH + cch] = (a0 + a1) + (a2 + a3);   // transposed
    } else {
        // ---- pair role: one 1024-row x (compacted) 64-cand tile ----
        int pb = b - NRBLK;                 // 0..575, block-uniform
        int g = 0;                          // group: w in [16g, 16g+15]
        while (8 * (g + 1) * (g + 2) <= pb) ++g;   // <=8 scalar iterations
        int off = pb - 8 * g * (g + 1);
        int wq = off / (g + 1);
        int w = (g << 4) + wq;              // j-word 0..127
        int h = off - wq * (g + 1);         // tile index 0..g
        int waveid = pb * WPB + (t >> 6);
        int lane = t & 63;
        __shared__ float4 cb[64];           // compacted valid candidates
        __shared__ float ca02[64];          // 0.2*area (screen threshold part)
        __shared__ unsigned long long cbk[64];
        __shared__ unsigned char cjr[64];   // rel index (0..63) of slot
        __shared__ unsigned long long jvS;
        __shared__ int nvjS;
        if (t < 64) {                       // exactly wave 0
            int j = (w << 6) + t;
            float2 cc = ((const float2*)conf)[j];
            bool v = (cc.x > THR_C) || (cc.y > THR_C);
            unsigned long long bv = __ballot(v);
            if (v) {
                int pos = __popcll(bv & ((1ull << t) - 1ull));
                float4 c = ((const float4*)bboxes)[j];
                cb[pos] = c;
                ca02[pos] = 0.2f * ((c.z - c.x) * (c.w - c.y));
                cbk[pos] = key_from(cc.x, cc.y, j);
                cjr[pos] = (unsigned char)t;
            }
            if (t == 0) { jvS = bv; nvjS = __popcll(bv); }
        }
        __syncthreads();
        unsigned long long jv = jvS;
        int nvj = nvjS;
        int ibase = h << 10;                // h * 1024
        int i0 = ibase + t;
        int i1 = i0 + 512;
        float2 cc0 = ((const float2*)conf)[i0];
        float2 cc1 = ((const float2*)conf)[i1];
        int km0, km1;                       // first allowed compacted slot (64=none)
        {
            int rel = i0 - (w << 6);
            bool iv = (cc0.x > THR_C) || (cc0.y > THR_C);
            if (!iv || rel >= 63)      km0 = 64;
            else if (rel >= 0)         km0 = __popcll(jv & ((2ull << rel) - 1ull));
            else                       km0 = 0;
        }
        {
            int rel = i1 - (w << 6);
            bool iv = (cc1.x > THR_C) || (cc1.y > THR_C);
            if (!iv || rel >= 63)      km1 = 64;
            else if (rel >= 0)         km1 = __popcll(jv & ((2ull << rel) - 1ull));
            else                       km1 = 0;
        }
        int wc = 0;                         // wave-uniform running edge count
        if (__any((km0 < nvj) || (km1 < nvj))) {
            float4 rb0 = ((const float4*)bboxes)[i0];
            float4 rb1 = ((const float4*)bboxes)[i1];
            float raF0 = (rb0.z - rb0.x) * (rb0.w - rb0.y);
            float raF1 = (rb1.z - rb1.x) * (rb1.w - rb1.y);
            float raS0 = 0.2f * raF0;
            float raS1 = 0.2f * raF1;
            unsigned long long ki0 = key_from(cc0.x, cc0.y, i0);
            unsigned long long ki1 = key_from(cc1.x, cc1.y, i1);
            unsigned long long bits0 = 0ull, bits1 = 0ull;
            for (int bb = 0; bb < nvj; ++bb) {
                float4 c = cb[bb];
                float s2 = ca02[bb];
                // row 0: clamped screen (disjoint pairs -> inter 0 -> reject)
                float iw0 = fminf(rb0.z, c.z) - fmaxf(rb0.x, c.x);
                float ih0 = fminf(rb0.w, c.w) - fmaxf(rb0.y, c.y);
                float inter0 = fmaxf(iw0, 0.0f) * fmaxf(ih0, 0.0f);
                if (inter0 > raS0 + s2) {
                    // exact reference arithmetic (bit-identical decision)
                    float caF = (c.z - c.x) * (c.w - c.y);
                    float iou = inter0 / (raF0 + caF - inter0 + EPS_C);
                    if (iou > IOU_THR_C) bits0 |= (1ull << bb);
                }
                // row 1
                float iw1 = fminf(rb1.z, c.z) - fmaxf(rb1.x, c.x);
                float ih1 = fminf(rb1.w, c.w) - fmaxf(rb1.y, c.y);
                float inter1 = fmaxf(iw1, 0.0f) * fmaxf(ih1, 0.0f);
                if (inter1 > raS1 + s2) {
                    float caF = (c.z - c.x) * (c.w - c.y);
                    float iou = inter1 / (raF1 + caF - inter1 + EPS_C);
                    if (iou > IOU_THR_C) bits1 |= (1ull << bb);
                }
            }
            // wave-local compaction into the wave's private slot (row 0)
            {
                unsigned long long m = (km0 >= 64) ? 0ull : (~0ull << km0);
                unsigned long long eb = bits0 & m;
                if (__any(eb != 0ull)) {
                    int ec = __popcll(eb);
                    int pre = ec;
#pragma unroll
                    for (int d = 1; d < 64; d <<= 1) {
                        int vv = __shfl_up(pre, d, 64);
                        if (lane >= d) pre += vv;
                    }
                    int tot = __shfl(pre, 63, 64);
                    int idx = wc + pre - ec;
                    unsigned long long tb = eb;
                    while (tb) {
                        int bb = __builtin_ctzll(tb); tb &= tb - 1;
                        if (idx < SLOT) {
                            int j = (w << 6) + (int)cjr[bb];
                            // smaller key = higher priority = suppressor
                            unsigned int e = (ki0 < cbk[bb])
                                             ? (((unsigned int)i0 << 13) | (unsigned int)j)
                                             : (((unsigned int)j << 13) | (unsigned int)i0);
                            wslot[(size_t)waveid * SLOT + idx] = e;
                        }
                        ++idx;
                    }
                    wc += tot;
                }
            }
            // row 1
            {
                unsigned long long m = (km1 >= 64) ? 0ull : (~0ull << km1);
                unsigned long long eb = bits1 & m;
                if (__any(eb != 0ull)) {
                    int ec = __popcll(eb);
                    int pre = ec;
#pragma unroll
                    for (int d = 1; d < 64; d <<= 1) {
                        int vv = __shfl_up(pre, d, 64);
                        if (lane >= d) pre += vv;
                    }
                    int tot = __shfl(pre, 63, 64);
                    int idx = wc + pre - ec;
                    unsigned long long tb = eb;
                    while (tb) {
                        int bb = __builtin_ctzll(tb); tb &= tb - 1;
                        if (idx < SLOT) {
                            int j = (w << 6) + (int)cjr[bb];
                            unsigned int e = (ki1 < cbk[bb])
                                             ? (((unsigned int)i1 << 13) | (unsigned int)j)
                                             : (((unsigned int)j << 13) | (unsigned int)i1);
                            wslot[(size_t)waveid * SLOT + idx] = e;
                        }
                        ++idx;
                    }
                    wc += tot;
                }
            }
        }
        if (lane == 0) wcnt[waveid] = (unsigned int)wc;  // >SLOT => sentinel
    }
}

// ---------------------------------------------------------------------------
// Stage B (single block): valid mask from validw -> wave-shfl prefix of wave
// counts (2 barriers) -> gather edges to LDS -> Jacobi-iterated greedy
// fixpoint (verified logic; k_new == k_old certifies exact greedy) ->
// transposed rank-sum -> scattered (N,6) output. Fallback (any wcnt>SLOT or
// total>LCAP; never on this data): exact serial greedy over rank order.
// ---------------------------------------------------------------------------
__global__ __launch_bounds__(NTHR) void stageB(const float* __restrict__ conf,
                                               const float* __restrict__ bboxes,
                                               const int* __restrict__ partial,
                                               const unsigned long long* __restrict__ validw,
                                               const unsigned int* __restrict__ wcnt,
                                               const unsigned int* __restrict__ wslot,
                                               float* __restrict__ out) {
    __shared__ unsigned int eL[LCAP];                       // 96 KiB
    __shared__ unsigned long long kL[NW], tL[NW], vL[NW];   // 3 KiB
    __shared__ int wsum[WPB];
    __shared__ int totS;
    __shared__ int chg[3];
    __shared__ int fbF, nvF;
    int t = threadIdx.x;
    int lane = t & 63;
    int wv = t >> 6;
    if (t == 0) { fbF = 0; nvF = 0; chg[0] = 0; chg[1] = 0; chg[2] = 0; }
    if (t < NW) { unsigned long long v = validw[t]; vL[t] = v; kL[t] = v; }
    // per-thread wave-count partial sums
    int nq[WSPT], myo[WSPT];
    int s = 0;
    bool ov = false;
#pragma unroll
    for (int q = 0; q < WSPT; ++q) {
        int v = (int)wcnt[t * WSPT + q];
        nq[q] = v; myo[q] = s; s += v;
        if (v > SLOT) ov = true;
    }
    // wave-level inclusive shfl scan (no barriers), then 8-entry block scan
    int pre = s;
#pragma unroll
    for (int d = 1; d < 64; d <<= 1) {
        int v = __shfl_up(pre, d, 64);
        if (lane >= d) pre += v;
    }
    if (lane == 63) wsum[wv] = pre;
    __syncthreads();                       // vL/kL/chg init + wsum published
    if (t == 0) {
        int acc = 0;
#pragma unroll
        for (int q = 0; q < WPB; ++q) { int v = wsum[q]; wsum[q] = acc; acc += v; }
        totS = acc;
    }
    __syncthreads();
    int ebase = wsum[wv] + (pre - s);      // exclusive base for this thread
    int totE = totS;
    if (ov || totE > LCAP) fbF = 1;        // benign same-value race
    __syncthreads();
    int fb = fbF;
    if (!fb) {
        // gather this thread's 9 waves' edges into contiguous LDS
#pragma unroll
        for (int q = 0; q < WSPT; ++q) {
            int w2 = t * WSPT + q;
            int off = ebase + myo[q];
            for (int k = 0; k < nq[q]; ++k)
                eL[off + k] = wslot[(size_t)w2 * SLOT + k];
        }
    }
    __syncthreads();
    if (!fb) {
        for (int it = 0; it < N_BOX; ++it) {
            if (t < NW) tL[t] = 0ull;
            __syncthreads();
            for (int e = t; e < totE; e += NTHR) {
                unsigned int ed = eL[e];
                int src = (int)(ed >> 13);
                if ((kL[src >> 6] >> (src & 63)) & 1ull) {
                    int tg = (int)(ed & 8191u);
                    atomicOr(&tL[tg >> 6], 1ull << (tg & 63));
                }
            }
            __syncthreads();
            if (t < NW) {
                unsigned long long nk = vL[t] & ~tL[t];
                if (nk != kL[t]) chg[it % 3] = 1;
                kL[t] = nk;
            }
            if (t == 0) chg[(it + 2) % 3] = 0;   // reset 2 barriers before reuse
            __syncthreads();
            if (chg[it % 3] == 0) break;         // uniform: read after barrier
        }
    } else {
        // fallback: build inverse permutation sinv[rank]=orig in eL, serial
        // greedy over rank order (one wave), then map kept ranks -> orig bits
        unsigned int* sinv = eL;
        for (int base = 0; base < N_BOX; base += NTHR) {
            int i = base + t;
            int r = 0;
#pragma unroll
            for (int c = 0; c < NCH; ++c) r += partial[i * NCH + c];
            sinv[r] = (unsigned int)i;
        }
        if (t < NW) { atomicAdd(&nvF, __popcll(vL[t])); tL[t] = 0ull; kL[t] = 0ull; }
        __syncthreads();
        int nv = nvF;
        if (t < 64) {
            for (int a = 0; a < nv - 1; ++a) {
                bool rem = (tL[a >> 6] >> (a & 63)) & 1ull;
                if (!rem) {
                    float4 r = ((const float4*)bboxes)[sinv[a]];
                    float ra = (r.z - r.x) * (r.w - r.y);
                    for (int b2 = a + 1 + t; b2 < nv; b2 += 64) {
                        float4 c = ((const float4*)bboxes)[sinv[b2]];
                        float ca = (c.z - c.x) * (c.w - c.y);
                        float iw = fminf(r.z, c.z) - fmaxf(r.x, c.x);
                        float ih = fminf(r.w, c.w) - fmaxf(r.y, c.y);
                        iw = fmaxf(iw, 0.0f);
                        ih = fmaxf(ih, 0.0f);
                        float inter = iw * ih;
                        float iou = inter / (ra + ca - inter + EPS_C);
                        if (iou > IOU_THR_C) atomicOr(&tL[b2 >> 6], 1ull << (b2 & 63));
                    }
                }
            }
        }
        __syncthreads();
        for (int a = t; a < nv; a += NTHR) {
            if (!((tL[a >> 6] >> (a & 63)) & 1ull)) {
                int ia = (int)sinv[a];
                atomicOr(&kL[ia >> 6], 1ull << (ia & 63));
            }
        }
    }
    __syncthreads();
    // output: row rank(i) <- kept ? [bbox_i*SCALER, conf_i] : zeros.
    // rank is a bijection, so every output row is written exactly once.
    // Suppressed/invalid rows are exactly 0.0 in the reference (positive
    // values * 0.0), so literal zeros are bit-identical. Transposed partial:
    // one contiguous 32 B (2x int4) read per row, coalesced across lanes.
    const int4* p4 = (const int4*)partial;
    for (int base = 0; base < N_BOX; base += NTHR) {
        int i = base + t;
        int4 pa = p4[i * 2];
        int4 pb2 = p4[i * 2 + 1];
        int r = ((pa.x + pa.y) + (pa.z + pa.w)) + ((pb2.x + pb2.y) + (pb2.z + pb2.w));
        bool kept = (kL[i >> 6] >> (i & 63)) & 1ull;
        if (kept) {
            float4 bx = ((const float4*)bboxes)[i];
            float2 cc = ((const float2*)conf)[i];
            out[r * 6 + 0] = bx.x * kScaler;
            out[r * 6 + 1] = bx.y * kScaler;
            out[r * 6 + 2] = bx.z * kScaler;
            out[r * 6 + 3] = bx.w * kScaler;
            out[r * 6 + 4] = cc.x;
            out[r * 6 + 5] = cc.y;
        } else {
            out[r * 6 + 0] = 0.0f;
            out[r * 6 + 1] = 0.0f;
            out[r * 6 + 2] = 0.0f;
            out[r * 6 + 3] = 0.0f;
            out[r * 6 + 4] = 0.0f;
            out[r * 6 + 5] = 0.0f;
        }
    }
}

extern "C" void kernel_launch(void* const* d_in, const int* in_sizes, int n_in,
                              void* d_out, int out_size, void* d_ws, size_t ws_size,
                              hipStream_t stream) {
    const float* cls_conf = (const float*)d_in[0];   // (8192, 2)
    const float* bboxes   = (const float*)d_in[1];   // (8192, 4)
    float* out = (float*)d_out;                      // (8192, 6)

    char* ws = (char*)d_ws;
    int*                partial = (int*)(ws + 0);                 // 256 KiB [i][8]
    unsigned int*       wcnt    = (unsigned int*)(ws + 262144);   //  18 KiB (4608)
    unsigned long long* validw  = (unsigned long long*)(ws + 282624); // 1 KiB
    unsigned int*       wslot   = (unsigned int*)(ws + 286720);   // 2.25 MiB (4608*128)
    (void)ws_size; (void)in_sizes; (void)n_in; (void)out_size;

    stageA<<<NRBLK + NPTILE, NTHR, 0, stream>>>(cls_conf, bboxes, partial, validw, wcnt, wslot);
    stageB<<<1, NTHR, 0, stream>>>(cls_conf, bboxes, partial, validw, wcnt, wslot, out);
}

// Round 8
// 95.214 us; speedup vs baseline: 1.4008x; 1.0514x over previous
//
#include <hip/hip_runtime.h>
#include <math.h>

#define N_BOX 8192
#define NW 128              // 8192 / 64 words per keep-mask row
#define NTHR 512
#define LCAP 24576          // edges staged in LDS (96 KiB)
#define NRBLK 128           // rank blocks: 16 ech x 8 cch (512 rows x 1024 cands)
#define NPTILE 576          // pair tiles: sum_w ceil((w+1)/16), 1024 rows x 64 cands
#define WPB 8               // waves per block (512/64)
#define NWAVE (NPTILE * WPB)// 4608 pair waves
#define SLOT 128            // edge slots per wave
#define WSPT (NWAVE / NTHR) // 9 wave-counts per stageB thread
#define NCH 8               // candidate chunks for rank stage (1024 each)
#define THR_C 0.7f
#define IOU_THR_C 0.5f
#define EPS_C 1e-9f

// SCALER = max(3508/1280, 2480/1280) computed in double then rounded to f32,
// matching numpy/jax float32 weak-typed scalar promotion.
__device__ __constant__ float kScaler = (float)(3508.0 / 1280.0);

// u64 key: ascending order == stable argsort(-masked_score). Unique (index in
// low bits). Invalid (-inf) keys sort strictly after all valid keys.
static __device__ __forceinline__ unsigned long long key_from(float c0, float c1, int i) {
    bool valid = (c0 > THR_C) || (c1 > THR_C);
    float ms = valid ? fmaxf(c0, c1) : -INFINITY;
    unsigned int u = __float_as_uint(ms);
    unsigned int m = (u & 0x80000000u) ? ~u : (u | 0x80000000u); // ascending map
    unsigned int d = ~m;                                          // descending key
    return ((unsigned long long)d << 32) | (unsigned int)i;
}

// ---------------------------------------------------------------------------
// Stage A (one launch, two block roles, no inter-stage dependency):
//  blocks [0, NRBLK): rank role, VALID-ONLY. Invalid boxes never need a rank
//    (all valid keys < all invalid keys, and rows >= nv of the output are
//    pure zeros), so both candidate keys and row keys are ballot-compacted
//    into LDS and the count loop runs valid x valid only (~4x less work).
//    rank(i) = #{valid j: key_j < key_i}, written TRANSPOSED partial[i*NCH+
//    cch] for valid i only. cch==0 blocks also ballot-write validw.
//  blocks [NRBLK, NRBLK+NPTILE): pair role, one tile each (perfect balance),
//    verbatim from the verified R7 kernel. Tile pb -> (w, h) closed form over
//    groups g = w>>4. Wave 0 COMPACTS valid candidates into LDS; per-row
//    constraint {j valid, j > i} becomes compacted slots k >= kmin(i).
//    CLAMPED screen inter > 0.2ra+0.2ca (iou>0.5 => inter > (ra+ca)/3 in
//    real arithmetic; 1.67x margin dwarfs fp error; disjoint pairs give
//    inter==0 -> rejected), so the exact reference division runs only for
//    gated pairs -> bit-identical decisions. Edge directed from the
//    smaller-key box; wcnt ALWAYS written (no init; >SLOT = fallback sentinel).
// ---------------------------------------------------------------------------
__global__ __launch_bounds__(NTHR) void stageA(const float* __restrict__ conf,
                                               const float* __restrict__ bboxes,
                                               int* __restrict__ partial,
                                               unsigned long long* __restrict__ validw,
                                               unsigned int* __restrict__ wcnt,
                                               unsigned int* __restrict__ wslot) {
    int b = blockIdx.x;
    int t = threadIdx.x;
    int lane = t & 63;
    if (b < NRBLK) {
        // ---- rank role: ~258 valid rows x ~516 valid candidates ----
        __align__(16) __shared__ unsigned long long ck[1024]; // compacted cand keys
        __shared__ unsigned long long rk[512];                // compacted row keys
        __shared__ int nvcS, nvrS;
        int ech = b >> 3;         // element chunk 0..15 (512 rows)
        int cch = b & 7;          // candidate chunk 0..7 (1024 cands)
        if (t == 0) { nvcS = 0; nvrS = 0; }
        __syncthreads();
        // candidates: 2 per thread, wave-aggregated compaction (order-free)
        for (int l = t; l < 1024; l += NTHR) {
            int j = (cch << 10) + l;
            float2 cc = ((const float2*)conf)[j];
            bool v = (cc.x > THR_C) || (cc.y > THR_C);
            unsigned long long bal = __ballot(v);
            int cnt = __popcll(bal);
            int base = 0;
            if (lane == 0 && cnt) base = atomicAdd(&nvcS, cnt);
            base = __shfl(base, 0, 64);
            if (v) ck[base + __popcll(bal & ((1ull << lane) - 1ull))] =
                       key_from(cc.x, cc.y, j);
        }
        // rows: 1 per thread; cch==0 also publishes validw
        {
            int i = (ech << 9) + t;
            float2 ci = ((const float2*)conf)[i];
            bool iv = (ci.x > THR_C) || (ci.y > THR_C);
            unsigned long long bal = __ballot(iv);
            if (cch == 0 && lane == 0) validw[i >> 6] = bal;
            int cnt = __popcll(bal);
            int base = 0;
            if (lane == 0 && cnt) base = atomicAdd(&nvrS, cnt);
            base = __shfl(base, 0, 64);
            if (iv) rk[base + __popcll(bal & ((1ull << lane) - 1ull))] =
                        key_from(ci.x, ci.y, i);
        }
        __syncthreads();
        int nvc = nvcS, nvr = nvrS;
        if (t < nvr) {
            unsigned long long ki = rk[t];
            const ulonglong2* ckp = (const ulonglong2*)ck;
            int a0 = 0, a1 = 0, a2 = 0, a3 = 0;
            int p = 0, np = nvc >> 1;              // u64 pairs
            for (; p + 2 <= np; p += 2) {
                ulonglong2 u = ckp[p];
                ulonglong2 v = ckp[p + 1];
                a0 += (u.x < ki) ? 1 : 0;
                a1 += (u.y < ki) ? 1 : 0;
                a2 += (v.x < ki) ? 1 : 0;
                a3 += (v.y < ki) ? 1 : 0;
            }
            int cnt = (a0 + a1) + (a2 + a3);
            for (int l = p << 1; l < nvc; ++l) cnt += (ck[l] < ki) ? 1 : 0;
            int i = (int)(ki & 0xffffffffull);     // key embeds orig index
            partial[i * NCH + cch] = cnt;          // transposed, valid rows only
        }
    } else {
        // ---- pair role: one 1024-row x (compacted) 64-cand tile (R7 verbatim) ----
        int pb = b - NRBLK;                 // 0..575, block-uniform
        int g = 0;                          // group: w in [16g, 16g+15]
        while (8 * (g + 1) * (g + 2) <= pb) ++g;   // <=8 scalar iterations
        int off = pb - 8 * g * (g + 1);
        int wq = off / (g + 1);
        int w = (g << 4) + wq;              // j-word 0..127
        int h = off - wq * (g + 1);         // tile index 0..g
        int waveid = pb * WPB + (t >> 6);
        __shared__ float4 cb[64];           // compacted valid candidates
        __shared__ float ca02[64];          // 0.2*area (screen threshold part)
        __shared__ unsigned long long cbk[64];
        __shared__ unsigned char cjr[64];   // rel index (0..63) of slot
        __shared__ unsigned long long jvS;
        __shared__ int nvjS;
        if (t < 64) {                       // exactly wave 0
            int j = (w << 6) + t;
            float2 cc = ((const float2*)conf)[j];
            bool v = (cc.x > THR_C) || (cc.y > THR_C);
            unsigned long long bv = __ballot(v);
            if (v) {
                int pos = __popcll(bv & ((1ull << t) - 1ull));
                float4 c = ((const float4*)bboxes)[j];
                cb[pos] = c;
                ca02[pos] = 0.2f * ((c.z - c.x) * (c.w - c.y));
                cbk[pos] = key_from(cc.x, cc.y, j);
                cjr[pos] = (unsigned char)t;
            }
            if (t == 0) { jvS = bv; nvjS = __popcll(bv); }
        }
        __syncthreads();
        unsigned long long jv = jvS;
        int nvj = nvjS;
        int ibase = h << 10;                // h * 1024
        int i0 = ibase + t;
        int i1 = i0 + 512;
        float2 cc0 = ((const float2*)conf)[i0];
        float2 cc1 = ((const float2*)conf)[i1];
        int km0, km1;                       // first allowed compacted slot (64=none)
        {
            int rel = i0 - (w << 6);
            bool iv = (cc0.x > THR_C) || (cc0.y > THR_C);
            if (!iv || rel >= 63)      km0 = 64;
            else if (rel >= 0)         km0 = __popcll(jv & ((2ull << rel) - 1ull));
            else                       km0 = 0;
        }
        {
            int rel = i1 - (w << 6);
            bool iv = (cc1.x > THR_C) || (cc1.y > THR_C);
            if (!iv || rel >= 63)      km1 = 64;
            else if (rel >= 0)         km1 = __popcll(jv & ((2ull << rel) - 1ull));
            else                       km1 = 0;
        }
        int wc = 0;                         // wave-uniform running edge count
        if (__any((km0 < nvj) || (km1 < nvj))) {
            float4 rb0 = ((const float4*)bboxes)[i0];
            float4 rb1 = ((const float4*)bboxes)[i1];
            float raF0 = (rb0.z - rb0.x) * (rb0.w - rb0.y);
            float raF1 = (rb1.z - rb1.x) * (rb1.w - rb1.y);
            float raS0 = 0.2f * raF0;
            float raS1 = 0.2f * raF1;
            unsigned long long ki0 = key_from(cc0.x, cc0.y, i0);
            unsigned long long ki1 = key_from(cc1.x, cc1.y, i1);
            unsigned long long bits0 = 0ull, bits1 = 0ull;
            for (int bb = 0; bb < nvj; ++bb) {
                float4 c = cb[bb];
                float s2 = ca02[bb];
                // row 0: clamped screen (disjoint pairs -> inter 0 -> reject)
                float iw0 = fminf(rb0.z, c.z) - fmaxf(rb0.x, c.x);
                float ih0 = fminf(rb0.w, c.w) - fmaxf(rb0.y, c.y);
                float inter0 = fmaxf(iw0, 0.0f) * fmaxf(ih0, 0.0f);
                if (inter0 > raS0 + s2) {
                    // exact reference arithmetic (bit-identical decision)
                    float caF = (c.z - c.x) * (c.w - c.y);
                    float iou = inter0 / (raF0 + caF - inter0 + EPS_C);
                    if (iou > IOU_THR_C) bits0 |= (1ull << bb);
                }
                // row 1
                float iw1 = fminf(rb1.z, c.z) - fmaxf(rb1.x, c.x);
                float ih1 = fminf(rb1.w, c.w) - fmaxf(rb1.y, c.y);
                float inter1 = fmaxf(iw1, 0.0f) * fmaxf(ih1, 0.0f);
                if (inter1 > raS1 + s2) {
                    float caF = (c.z - c.x) * (c.w - c.y);
                    float iou = inter1 / (raF1 + caF - inter1 + EPS_C);
                    if (iou > IOU_THR_C) bits1 |= (1ull << bb);
                }
            }
            // wave-local compaction into the wave's private slot (row 0)
            {
                unsigned long long m = (km0 >= 64) ? 0ull : (~0ull << km0);
                unsigned long long eb = bits0 & m;
                if (__any(eb != 0ull)) {
                    int ec = __popcll(eb);
                    int pre = ec;
#pragma unroll
                    for (int d = 1; d < 64; d <<= 1) {
                        int vv = __shfl_up(pre, d, 64);
                        if (lane >= d) pre += vv;
                    }
                    int tot = __shfl(pre, 63, 64);
                    int idx = wc + pre - ec;
                    unsigned long long tb = eb;
                    while (tb) {
                        int bb = __builtin_ctzll(tb); tb &= tb - 1;
                        if (idx < SLOT) {
                            int j = (w << 6) + (int)cjr[bb];
                            // smaller key = higher priority = suppressor
                            unsigned int e = (ki0 < cbk[bb])
                                             ? (((unsigned int)i0 << 13) | (unsigned int)j)
                                             : (((unsigned int)j << 13) | (unsigned int)i0);
                            wslot[(size_t)waveid * SLOT + idx] = e;
                        }
                        ++idx;
                    }
                    wc += tot;
                }
            }
            // row 1
            {
                unsigned long long m = (km1 >= 64) ? 0ull : (~0ull << km1);
                unsigned long long eb = bits1 & m;
                if (__any(eb != 0ull)) {
                    int ec = __popcll(eb);
                    int pre = ec;
#pragma unroll
                    for (int d = 1; d < 64; d <<= 1) {
                        int vv = __shfl_up(pre, d, 64);
                        if (lane >= d) pre += vv;
                    }
                    int tot = __shfl(pre, 63, 64);
                    int idx = wc + pre - ec;
                    unsigned long long tb = eb;
                    while (tb) {
                        int bb = __builtin_ctzll(tb); tb &= tb - 1;
                        if (idx < SLOT) {
                            int j = (w << 6) + (int)cjr[bb];
                            unsigned int e = (ki1 < cbk[bb])
                                             ? (((unsigned int)i1 << 13) | (unsigned int)j)
                                             : (((unsigned int)j << 13) | (unsigned int)i1);
                            wslot[(size_t)waveid * SLOT + idx] = e;
                        }
                        ++idx;
                    }
                    wc += tot;
                }
            }
        }
        if (lane == 0) wcnt[waveid] = (unsigned int)wc;  // >SLOT => sentinel
    }
}

// ---------------------------------------------------------------------------
// Stage B (single block): valid mask + nv -> wave-shfl prefix of wave counts
// -> gather edges to LDS -> build sinv[rank]=orig (valid rows only) ->
// Jacobi-iterated greedy fixpoint (verified; k_new == k_old certifies exact
// greedy) -> DENSE output: row r<nv from sinv, rows >= nv are literal zeros.
// Fallback (any wcnt>SLOT or totE>LCAP; never on this data): exact serial
// greedy over sinv rank order, IoU recomputed on the fly.
// ---------------------------------------------------------------------------
__global__ __launch_bounds__(NTHR) void stageB(const float* __restrict__ conf,
                                               const float* __restrict__ bboxes,
                                               const int* __restrict__ partial,
                                               const unsigned long long* __restrict__ validw,
                                               const unsigned int* __restrict__ wcnt,
                                               const unsigned int* __restrict__ wslot,
                                               float* __restrict__ out) {
    __shared__ unsigned int eL[LCAP];                       // 96 KiB
    __shared__ int sinv[N_BOX];                             // 32 KiB
    __shared__ unsigned long long kL[NW], tL[NW], vL[NW];   // 3 KiB
    __shared__ int wsum[WPB];
    __shared__ int totS;
    __shared__ int chg[3];
    __shared__ int fbF, nvF;
    int t = threadIdx.x;
    int lane = t & 63;
    int wv = t >> 6;
    if (t == 0) { fbF = 0; nvF = 0; chg[0] = 0; chg[1] = 0; chg[2] = 0; }
    if (t < NW) {
        unsigned long long v = validw[t];
        vL[t] = v; kL[t] = v;
        atomicAdd(&nvF, __popcll(v));
    }
    // per-thread wave-count partial sums
    int nq[WSPT], myo[WSPT];
    int s = 0;
    bool ov = false;
#pragma unroll
    for (int q = 0; q < WSPT; ++q) {
        int v = (int)wcnt[t * WSPT + q];
        nq[q] = v; myo[q] = s; s += v;
        if (v > SLOT) ov = true;
    }
    // wave-level inclusive shfl scan (no barriers), then 8-entry block scan
    int pre = s;
#pragma unroll
    for (int d = 1; d < 64; d <<= 1) {
        int v = __shfl_up(pre, d, 64);
        if (lane >= d) pre += v;
    }
    if (lane == 63) wsum[wv] = pre;
    __syncthreads();                       // vL/kL/nvF/chg init + wsum published
    if (t == 0) {
        int acc = 0;
#pragma unroll
        for (int q = 0; q < WPB; ++q) { int v = wsum[q]; wsum[q] = acc; acc += v; }
        totS = acc;
    }
    __syncthreads();
    int ebase = wsum[wv] + (pre - s);      // exclusive base for this thread
    int totE = totS;
    if (ov || totE > LCAP) fbF = 1;        // benign same-value race
    // build sinv: rank -> orig index, valid rows only (transposed partial:
    // one contiguous 32 B read per valid row)
    {
        const int4* p4 = (const int4*)partial;
        for (int base = 0; base < N_BOX; base += NTHR) {
            int i = base + t;
            if ((vL[i >> 6] >> (i & 63)) & 1ull) {
                int4 pa = p4[i * 2];
                int4 pb2 = p4[i * 2 + 1];
                int r = ((pa.x + pa.y) + (pa.z + pa.w))
                      + ((pb2.x + pb2.y) + (pb2.z + pb2.w));
                sinv[r] = i;
            }
        }
    }
    __syncthreads();
    int fb = fbF;
    if (!fb) {
        // gather this thread's 9 waves' edges into contiguous LDS
#pragma unroll
        for (int q = 0; q < WSPT; ++q) {
            int w2 = t * WSPT + q;
            int off = ebase + myo[q];
            for (int k = 0; k < nq[q]; ++k)
                eL[off + k] = wslot[(size_t)w2 * SLOT + k];
        }
    }
    __syncthreads();
    if (!fb) {
        for (int it = 0; it < N_BOX; ++it) {
            if (t < NW) tL[t] = 0ull;
            __syncthreads();
            for (int e = t; e < totE; e += NTHR) {
                unsigned int ed = eL[e];
                int src = (int)(ed >> 13);
                if ((kL[src >> 6] >> (src & 63)) & 1ull) {
                    int tg = (int)(ed & 8191u);
                    atomicOr(&tL[tg >> 6], 1ull << (tg & 63));
                }
            }
            __syncthreads();
            if (t < NW) {
                unsigned long long nk = vL[t] & ~tL[t];
                if (nk != kL[t]) chg[it % 3] = 1;
                kL[t] = nk;
            }
            if (t == 0) chg[(it + 2) % 3] = 0;   // reset 2 barriers before reuse
            __syncthreads();
            if (chg[it % 3] == 0) break;         // uniform: read after barrier
        }
    } else {
        // fallback: serial greedy over rank order via sinv (one wave)
        if (t < NW) { tL[t] = 0ull; kL[t] = 0ull; }
        __syncthreads();
        int nv = nvF;
        if (t < 64) {
            for (int a = 0; a < nv - 1; ++a) {
                bool rem = (tL[a >> 6] >> (a & 63)) & 1ull;
                if (!rem) {
                    float4 r = ((const float4*)bboxes)[sinv[a]];
                    float ra = (r.z - r.x) * (r.w - r.y);
                    for (int b2 = a + 1 + t; b2 < nv; b2 += 64) {
                        float4 c = ((const float4*)bboxes)[sinv[b2]];
                        float ca = (c.z - c.x) * (c.w - c.y);
                        float iw = fminf(r.z, c.z) - fmaxf(r.x, c.x);
                        float ih = fminf(r.w, c.w) - fmaxf(r.y, c.y);
                        iw = fmaxf(iw, 0.0f);
                        ih = fmaxf(ih, 0.0f);
                        float inter = iw * ih;
                        float iou = inter / (ra + ca - inter + EPS_C);
                        if (iou > IOU_THR_C) atomicOr(&tL[b2 >> 6], 1ull << (b2 & 63));
                    }
                }
            }
        }
        __syncthreads();
        for (int a = t; a < nvF; a += NTHR) {
            if (!((tL[a >> 6] >> (a & 63)) & 1ull)) {
                int ia = sinv[a];
                atomicOr(&kL[ia >> 6], 1ull << (ia & 63));
            }
        }
    }
    __syncthreads();
    // DENSE output: row r < nv <- box sinv[r] (kept ? values : zeros);
    // rows >= nv come only from invalid boxes -> exactly 0.0 in the reference
    // (positive values * 0.0), so literal zeros are bit-identical.
    int nv = nvF;
    for (int base = 0; base < N_BOX; base += NTHR) {
        int r = base + t;
        bool kept = false;
        int i = 0;
        if (r < nv) {
            i = sinv[r];
            kept = (kL[i >> 6] >> (i & 63)) & 1ull;
        }
        if (kept) {
            float4 bx = ((const float4*)bboxes)[i];
            float2 cc = ((const float2*)conf)[i];
            out[r * 6 + 0] = bx.x * kScaler;
            out[r * 6 + 1] = bx.y * kScaler;
            out[r * 6 + 2] = bx.z * kScaler;
            out[r * 6 + 3] = bx.w * kScaler;
            out[r * 6 + 4] = cc.x;
            out[r * 6 + 5] = cc.y;
        } else {
            out[r * 6 + 0] = 0.0f;
            out[r * 6 + 1] = 0.0f;
            out[r * 6 + 2] = 0.0f;
            out[r * 6 + 3] = 0.0f;
            out[r * 6 + 4] = 0.0f;
            out[r * 6 + 5] = 0.0f;
        }
    }
}

extern "C" void kernel_launch(void* const* d_in, const int* in_sizes, int n_in,
                              void* d_out, int out_size, void* d_ws, size_t ws_size,
                              hipStream_t stream) {
    const float* cls_conf = (const float*)d_in[0];   // (8192, 2)
    const float* bboxes   = (const float*)d_in[1];   // (8192, 4)
    float* out = (float*)d_out;                      // (8192, 6)

    char* ws = (char*)d_ws;
    int*                partial = (int*)(ws + 0);                 // 256 KiB [i][8]
    unsigned int*       wcnt    = (unsigned int*)(ws + 262144);   //  18 KiB (4608)
    unsigned long long* validw  = (unsigned long long*)(ws + 282624); // 1 KiB
    unsigned int*       wslot   = (unsigned int*)(ws + 286720);   // 2.25 MiB (4608*128)
    (void)ws_size; (void)in_sizes; (void)n_in; (void)out_size;

    stageA<<<NRBLK + NPTILE, NTHR, 0, stream>>>(cls_conf, bboxes, partial, validw, wcnt, wslot);
    stageB<<<1, NTHR, 0, stream>>>(cls_conf, bboxes, partial, validw, wcnt, wslot, out);
}

// Round 9
// 94.957 us; speedup vs baseline: 1.4045x; 1.0027x over previous
//
#include <hip/hip_runtime.h>
#include <math.h>

#define N_BOX 8192
#define NW 128              // 8192 / 64 words per keep-mask row
#define NTHR 512
#define LCAP 24576          // edges staged in LDS (96 KiB)
#define NRBLK 128           // rank blocks: 16 ech x 8 cch (512 rows x 1024 cands)
#define NPTILE 576          // pair tiles: sum_w ceil((w+1)/16), 1024 rows x 64 cands
#define WPB 8               // waves per block (512/64)
#define NWAVE (NPTILE * WPB)// 4608 pair waves
#define SLOT 128            // edge slots per wave
#define WSPT (NWAVE / NTHR) // 9 wave-counts per stageB thread
#define NCH 8               // candidate chunks for rank stage (1024 each)
#define THR_C 0.7f
#define IOU_THR_C 0.5f
#define EPS_C 1e-9f

// SCALER = max(3508/1280, 2480/1280) computed in double then rounded to f32,
// matching numpy/jax float32 weak-typed scalar promotion.
__device__ __constant__ float kScaler = (float)(3508.0 / 1280.0);

// u64 key: ascending order == stable argsort(-masked_score). Unique (index in
// low bits). Invalid (-inf) keys sort strictly after all valid keys.
static __device__ __forceinline__ unsigned long long key_from(float c0, float c1, int i) {
    bool valid = (c0 > THR_C) || (c1 > THR_C);
    float ms = valid ? fmaxf(c0, c1) : -INFINITY;
    unsigned int u = __float_as_uint(ms);
    unsigned int m = (u & 0x80000000u) ? ~u : (u | 0x80000000u); // ascending map
    unsigned int d = ~m;                                          // descending key
    return ((unsigned long long)d << 32) | (unsigned int)i;
}

// ---------------------------------------------------------------------------
// Stage A (one launch, two block roles, no inter-stage dependency):
//  blocks [0, NRBLK): rank role, VALID-ONLY, FULL-LANE. Both candidate and
//    row keys are ballot-compacted into LDS; each row's count is split over
//    TWO threads (slot = 2*row+half) so all 512 lanes stay busy (~258
//    compares each); halves summed via LDS rcnt. rank(i) = #{valid j: key_j
//    < key_i}, written TRANSPOSED partial[i*NCH+cch] for valid rows only.
//    cch==0 blocks also ballot-write validw.
//  blocks [NRBLK, NRBLK+NPTILE): pair role, one tile each (perfect balance),
//    verbatim from the verified R8 kernel. Tile pb -> (w, h) closed form over
//    groups g = w>>4. Wave 0 COMPACTS valid candidates into LDS; per-row
//    constraint {j valid, j > i} becomes compacted slots k >= kmin(i).
//    CLAMPED screen inter > 0.2ra+0.2ca (iou>0.5 => inter > (ra+ca)/3 in
//    real arithmetic; 1.67x margin dwarfs fp error; disjoint pairs give
//    inter==0 -> rejected), so the exact reference division runs only for
//    gated pairs -> bit-identical decisions. Edge directed from the
//    smaller-key box; wcnt ALWAYS written (no init; >SLOT = fallback sentinel).
// ---------------------------------------------------------------------------
__global__ __launch_bounds__(NTHR) void stageA(const float* __restrict__ conf,
                                               const float* __restrict__ bboxes,
                                               int* __restrict__ partial,
                                               unsigned long long* __restrict__ validw,
                                               unsigned int* __restrict__ wcnt,
                                               unsigned int* __restrict__ wslot) {
    int b = blockIdx.x;
    int t = threadIdx.x;
    int lane = t & 63;
    if (b < NRBLK) {
        // ---- rank role: ~258 valid rows x ~516 valid candidates, 2 thr/row ----
        __align__(16) __shared__ unsigned long long ck[1024]; // compacted cand keys
        __shared__ unsigned long long rk[512];                // compacted row keys
        __shared__ int rcnt[1024];                            // per (row,half) counts
        __shared__ int nvcS, nvrS;
        int ech = b >> 3;         // element chunk 0..15 (512 rows)
        int cch = b & 7;          // candidate chunk 0..7 (1024 cands)
        if (t == 0) { nvcS = 0; nvrS = 0; }
        __syncthreads();
        // candidates: 2 per thread, wave-aggregated compaction (order-free)
        for (int l = t; l < 1024; l += NTHR) {
            int j = (cch << 10) + l;
            float2 cc = ((const float2*)conf)[j];
            bool v = (cc.x > THR_C) || (cc.y > THR_C);
            unsigned long long bal = __ballot(v);
            int cnt = __popcll(bal);
            int base = 0;
            if (lane == 0 && cnt) base = atomicAdd(&nvcS, cnt);
            base = __shfl(base, 0, 64);
            if (v) ck[base + __popcll(bal & ((1ull << lane) - 1ull))] =
                       key_from(cc.x, cc.y, j);
        }
        // rows: 1 per thread; cch==0 also publishes validw
        {
            int i = (ech << 9) + t;
            float2 ci = ((const float2*)conf)[i];
            bool iv = (ci.x > THR_C) || (ci.y > THR_C);
            unsigned long long bal = __ballot(iv);
            if (cch == 0 && lane == 0) validw[i >> 6] = bal;
            int cnt = __popcll(bal);
            int base = 0;
            if (lane == 0 && cnt) base = atomicAdd(&nvrS, cnt);
            base = __shfl(base, 0, 64);
            if (iv) rk[base + __popcll(bal & ((1ull << lane) - 1ull))] =
                        key_from(ci.x, ci.y, i);
        }
        __syncthreads();
        int nvc = nvcS, nvr = nvrS;
        int npairs = nvc >> 1;                 // ulonglong2 count
        int nslots = nvr << 1;
        const ulonglong2* ckp = (const ulonglong2*)ck;
        for (int slot = t; slot < nslots; slot += NTHR) {
            int row = slot >> 1, half = slot & 1;
            unsigned long long ki = rk[row];
            int lo = half ? (npairs >> 1) : 0;
            int hi = half ? npairs : (npairs >> 1);
            int a0 = 0, a1 = 0;
#pragma unroll 4
            for (int p = lo; p < hi; ++p) {
                ulonglong2 u = ckp[p];
                a0 += (u.x < ki) ? 1 : 0;
                a1 += (u.y < ki) ? 1 : 0;
            }
            int cnt = a0 + a1;
            if (half) {                        // odd-nvc tail element
                for (int l = npairs << 1; l < nvc; ++l) cnt += (ck[l] < ki) ? 1 : 0;
            }
            rcnt[slot] = cnt;
        }
        __syncthreads();
        for (int row = t; row < nvr; row += NTHR) {
            unsigned long long ki = rk[row];
            int i = (int)(ki & 0xffffffffull); // key embeds orig index
            partial[i * NCH + cch] = rcnt[2 * row] + rcnt[2 * row + 1];
        }
    } else {
        // ---- pair role: one 1024-row x (compacted) 64-cand tile (R8 verbatim) ----
        int pb = b - NRBLK;                 // 0..575, block-uniform
        int g = 0;                          // group: w in [16g, 16g+15]
        while (8 * (g + 1) * (g + 2) <= pb) ++g;   // <=8 scalar iterations
        int off = pb - 8 * g * (g + 1);
        int wq = off / (g + 1);
        int w = (g << 4) + wq;              // j-word 0..127
        int h = off - wq * (g + 1);         // tile index 0..g
        int waveid = pb * WPB + (t >> 6);
        __shared__ float4 cb[64];           // compacted valid candidates
        __shared__ float ca02[64];          // 0.2*area (screen threshold part)
        __shared__ unsigned long long cbk[64];
        __shared__ unsigned char cjr[64];   // rel index (0..63) of slot
        __shared__ unsigned long long jvS;
        __shared__ int nvjS;
        if (t < 64) {                       // exactly wave 0
            int j = (w << 6) + t;
            float2 cc = ((const float2*)conf)[j];
            bool v = (cc.x > THR_C) || (cc.y > THR_C);
            unsigned long long bv = __ballot(v);
            if (v) {
                int pos = __popcll(bv & ((1ull << t) - 1ull));
                float4 c = ((const float4*)bboxes)[j];
                cb[pos] = c;
                ca02[pos] = 0.2f * ((c.z - c.x) * (c.w - c.y));
                cbk[pos] = key_from(cc.x, cc.y, j);
                cjr[pos] = (unsigned char)t;
            }
            if (t == 0) { jvS = bv; nvjS = __popcll(bv); }
        }
        __syncthreads();
        unsigned long long jv = jvS;
        int nvj = nvjS;
        int ibase = h << 10;                // h * 1024
        int i0 = ibase + t;
        int i1 = i0 + 512;
        float2 cc0 = ((const float2*)conf)[i0];
        float2 cc1 = ((const float2*)conf)[i1];
        int km0, km1;                       // first allowed compacted slot (64=none)
        {
            int rel = i0 - (w << 6);
            bool iv = (cc0.x > THR_C) || (cc0.y > THR_C);
            if (!iv || rel >= 63)      km0 = 64;
            else if (rel >= 0)         km0 = __popcll(jv & ((2ull << rel) - 1ull));
            else                       km0 = 0;
        }
        {
            int rel = i1 - (w << 6);
            bool iv = (cc1.x > THR_C) || (cc1.y > THR_C);
            if (!iv || rel >= 63)      km1 = 64;
            else if (rel >= 0)         km1 = __popcll(jv & ((2ull << rel) - 1ull));
            else                       km1 = 0;
        }
        int wc = 0;                         // wave-uniform running edge count
        if (__any((km0 < nvj) || (km1 < nvj))) {
            float4 rb0 = ((const float4*)bboxes)[i0];
            float4 rb1 = ((const float4*)bboxes)[i1];
            float raF0 = (rb0.z - rb0.x) * (rb0.w - rb0.y);
            float raF1 = (rb1.z - rb1.x) * (rb1.w - rb1.y);
            float raS0 = 0.2f * raF0;
            float raS1 = 0.2f * raF1;
            unsigned long long ki0 = key_from(cc0.x, cc0.y, i0);
            unsigned long long ki1 = key_from(cc1.x, cc1.y, i1);
            unsigned long long bits0 = 0ull, bits1 = 0ull;
            for (int bb = 0; bb < nvj; ++bb) {
                float4 c = cb[bb];
                float s2 = ca02[bb];
                // row 0: clamped screen (disjoint pairs -> inter 0 -> reject)
                float iw0 = fminf(rb0.z, c.z) - fmaxf(rb0.x, c.x);
                float ih0 = fminf(rb0.w, c.w) - fmaxf(rb0.y, c.y);
                float inter0 = fmaxf(iw0, 0.0f) * fmaxf(ih0, 0.0f);
                if (inter0 > raS0 + s2) {
                    // exact reference arithmetic (bit-identical decision)
                    float caF = (c.z - c.x) * (c.w - c.y);
                    float iou = inter0 / (raF0 + caF - inter0 + EPS_C);
                    if (iou > IOU_THR_C) bits0 |= (1ull << bb);
                }
                // row 1
                float iw1 = fminf(rb1.z, c.z) - fmaxf(rb1.x, c.x);
                float ih1 = fminf(rb1.w, c.w) - fmaxf(rb1.y, c.y);
                float inter1 = fmaxf(iw1, 0.0f) * fmaxf(ih1, 0.0f);
                if (inter1 > raS1 + s2) {
                    float caF = (c.z - c.x) * (c.w - c.y);
                    float iou = inter1 / (raF1 + caF - inter1 + EPS_C);
                    if (iou > IOU_THR_C) bits1 |= (1ull << bb);
                }
            }
            // wave-local compaction into the wave's private slot (row 0)
            {
                unsigned long long m = (km0 >= 64) ? 0ull : (~0ull << km0);
                unsigned long long eb = bits0 & m;
                if (__any(eb != 0ull)) {
                    int ec = __popcll(eb);
                    int pre = ec;
#pragma unroll
                    for (int d = 1; d < 64; d <<= 1) {
                        int vv = __shfl_up(pre, d, 64);
                        if (lane >= d) pre += vv;
                    }
                    int tot = __shfl(pre, 63, 64);
                    int idx = wc + pre - ec;
                    unsigned long long tb = eb;
                    while (tb) {
                        int bb = __builtin_ctzll(tb); tb &= tb - 1;
                        if (idx < SLOT) {
                            int j = (w << 6) + (int)cjr[bb];
                            // smaller key = higher priority = suppressor
                            unsigned int e = (ki0 < cbk[bb])
                                             ? (((unsigned int)i0 << 13) | (unsigned int)j)
                                             : (((unsigned int)j << 13) | (unsigned int)i0);
                            wslot[(size_t)waveid * SLOT + idx] = e;
                        }
                        ++idx;
                    }
                    wc += tot;
                }
            }
            // row 1
            {
                unsigned long long m = (km1 >= 64) ? 0ull : (~0ull << km1);
                unsigned long long eb = bits1 & m;
                if (__any(eb != 0ull)) {
                    int ec = __popcll(eb);
                    int pre = ec;
#pragma unroll
                    for (int d = 1; d < 64; d <<= 1) {
                        int vv = __shfl_up(pre, d, 64);
                        if (lane >= d) pre += vv;
                    }
                    int tot = __shfl(pre, 63, 64);
                    int idx = wc + pre - ec;
                    unsigned long long tb = eb;
                    while (tb) {
                        int bb = __builtin_ctzll(tb); tb &= tb - 1;
                        if (idx < SLOT) {
                            int j = (w << 6) + (int)cjr[bb];
                            unsigned int e = (ki1 < cbk[bb])
                                             ? (((unsigned int)i1 << 13) | (unsigned int)j)
                                             : (((unsigned int)j << 13) | (unsigned int)i1);
                            wslot[(size_t)waveid * SLOT + idx] = e;
                        }
                        ++idx;
                    }
                    wc += tot;
                }
            }
        }
        if (lane == 0) wcnt[waveid] = (unsigned int)wc;  // >SLOT => sentinel
    }
}

// ---------------------------------------------------------------------------
// Stage B (single block): valid mask + nv -> wave-shfl prefix of wave counts
// (COALESCED mapping: thread t owns waves q*512+t; edge order in eL is
// irrelevant to the fixpoint, so any bijection is exact) -> gather edges to
// LDS -> build sinv[rank]=orig (valid rows only) -> Jacobi-iterated greedy
// fixpoint, 2 barriers/iter (tL re-zeroed in the update phase by its owner
// thread; k_new == k_old certifies exact greedy) -> DENSE output: row r<nv
// from sinv, rows >= nv are literal zeros. Fallback (any wcnt>SLOT or
// totE>LCAP; never on this data): exact serial greedy over sinv rank order.
// ---------------------------------------------------------------------------
__global__ __launch_bounds__(NTHR) void stageB(const float* __restrict__ conf,
                                               const float* __restrict__ bboxes,
                                               const int* __restrict__ partial,
                                               const unsigned long long* __restrict__ validw,
                                               const unsigned int* __restrict__ wcnt,
                                               const unsigned int* __restrict__ wslot,
                                               float* __restrict__ out) {
    __shared__ unsigned int eL[LCAP];                       // 96 KiB
    __shared__ int sinv[N_BOX];                             // 32 KiB
    __shared__ unsigned long long kL[NW], tL[NW], vL[NW];   // 3 KiB
    __shared__ int wsum[WPB];
    __shared__ int totS;
    __shared__ int chg[3];
    __shared__ int fbF, nvF;
    int t = threadIdx.x;
    int lane = t & 63;
    int wv = t >> 6;
    if (t == 0) { fbF = 0; nvF = 0; chg[0] = 0; chg[1] = 0; chg[2] = 0; }
    if (t < NW) {
        unsigned long long v = validw[t];
        vL[t] = v; kL[t] = v; tL[t] = 0ull;
        atomicAdd(&nvF, __popcll(v));
    }
    // per-thread wave-count partial sums; thread t owns waves {q*512+t}
    int nq[WSPT], myo[WSPT];
    int s = 0;
    bool ov = false;
#pragma unroll
    for (int q = 0; q < WSPT; ++q) {
        int v = (int)wcnt[q * NTHR + t];   // coalesced
        nq[q] = v; myo[q] = s; s += v;
        if (v > SLOT) ov = true;
    }
    // wave-level inclusive shfl scan (no barriers), then 8-entry block scan
    int pre = s;
#pragma unroll
    for (int d = 1; d < 64; d <<= 1) {
        int v = __shfl_up(pre, d, 64);
        if (lane >= d) pre += v;
    }
    if (lane == 63) wsum[wv] = pre;
    __syncthreads();                       // vL/kL/tL/nvF/chg init + wsum published
    if (t == 0) {
        int acc = 0;
#pragma unroll
        for (int q = 0; q < WPB; ++q) { int v = wsum[q]; wsum[q] = acc; acc += v; }
        totS = acc;
    }
    __syncthreads();
    int ebase = wsum[wv] + (pre - s);      // exclusive base for this thread
    int totE = totS;
    if (ov || totE > LCAP) fbF = 1;        // benign same-value race
    // build sinv: rank -> orig index, valid rows only (transposed partial:
    // one contiguous 32 B read per valid row)
    {
        const int4* p4 = (const int4*)partial;
        for (int base = 0; base < N_BOX; base += NTHR) {
            int i = base + t;
            if ((vL[i >> 6] >> (i & 63)) & 1ull) {
                int4 pa = p4[i * 2];
                int4 pb2 = p4[i * 2 + 1];
                int r = ((pa.x + pa.y) + (pa.z + pa.w))
                      + ((pb2.x + pb2.y) + (pb2.z + pb2.w));
                sinv[r] = i;
            }
        }
    }
    __syncthreads();
    int fb = fbF;
    if (!fb) {
        // gather this thread's 9 waves' edges into contiguous LDS
#pragma unroll
        for (int q = 0; q < WSPT; ++q) {
            int w2 = q * NTHR + t;
            int off = ebase + myo[q];
            for (int k = 0; k < nq[q]; ++k)
                eL[off + k] = wslot[(size_t)w2 * SLOT + k];
        }
    }
    __syncthreads();
    if (!fb) {
        for (int it = 0; it < N_BOX; ++it) {
            for (int e = t; e < totE; e += NTHR) {
                unsigned int ed = eL[e];
                int src = (int)(ed >> 13);
                if ((kL[src >> 6] >> (src & 63)) & 1ull) {
                    int tg = (int)(ed & 8191u);
                    atomicOr(&tL[tg >> 6], 1ull << (tg & 63));
                }
            }
            __syncthreads();                     // sweep done
            if (t < NW) {
                unsigned long long tt = tL[t];
                unsigned long long nk = vL[t] & ~tt;
                if (nk != kL[t]) chg[it % 3] = 1;
                kL[t] = nk;
                tL[t] = 0ull;                    // re-zero for next sweep
            }
            if (t == 0) chg[(it + 2) % 3] = 0;   // reset 2 iters before reuse
            __syncthreads();                     // update visible
            if (chg[it % 3] == 0) break;         // uniform: read after barrier
        }
    } else {
        // fallback: serial greedy over rank order via sinv (one wave)
        if (t < NW) { tL[t] = 0ull; kL[t] = 0ull; }
        __syncthreads();
        int nv = nvF;
        if (t < 64) {
            for (int a = 0; a < nv - 1; ++a) {
                bool rem = (tL[a >> 6] >> (a & 63)) & 1ull;
                if (!rem) {
                    float4 r = ((const float4*)bboxes)[sinv[a]];
                    float ra = (r.z - r.x) * (r.w - r.y);
                    for (int b2 = a + 1 + t; b2 < nv; b2 += 64) {
                        float4 c = ((const float4*)bboxes)[sinv[b2]];
                        float ca = (c.z - c.x) * (c.w - c.y);
                        float iw = fminf(r.z, c.z) - fmaxf(r.x, c.x);
                        float ih = fminf(r.w, c.w) - fmaxf(r.y, c.y);
                        iw = fmaxf(iw, 0.0f);
                        ih = fmaxf(ih, 0.0f);
                        float inter = iw * ih;
                        float iou = inter / (ra + ca - inter + EPS_C);
                        if (iou > IOU_THR_C) atomicOr(&tL[b2 >> 6], 1ull << (b2 & 63));
                    }
                }
            }
        }
        __syncthreads();
        for (int a = t; a < nvF; a += NTHR) {
            if (!((tL[a >> 6] >> (a & 63)) & 1ull)) {
                int ia = sinv[a];
                atomicOr(&kL[ia >> 6], 1ull << (ia & 63));
            }
        }
    }
    __syncthreads();
    // DENSE output: row r < nv <- box sinv[r] (kept ? values : zeros);
    // rows >= nv come only from invalid boxes -> exactly 0.0 in the reference
    // (positive values * 0.0), so literal zeros are bit-identical.
    int nv = nvF;
    for (int base = 0; base < N_BOX; base += NTHR) {
        int r = base + t;
        bool kept = false;
        int i = 0;
        if (r < nv) {
            i = sinv[r];
            kept = (kL[i >> 6] >> (i & 63)) & 1ull;
        }
        if (kept) {
            float4 bx = ((const float4*)bboxes)[i];
            float2 cc = ((const float2*)conf)[i];
            out[r * 6 + 0] = bx.x * kScaler;
            out[r * 6 + 1] = bx.y * kScaler;
            out[r * 6 + 2] = bx.z * kScaler;
            out[r * 6 + 3] = bx.w * kScaler;
            out[r * 6 + 4] = cc.x;
            out[r * 6 + 5] = cc.y;
        } else {
            out[r * 6 + 0] = 0.0f;
            out[r * 6 + 1] = 0.0f;
            out[r * 6 + 2] = 0.0f;
            out[r * 6 + 3] = 0.0f;
            out[r * 6 + 4] = 0.0f;
            out[r * 6 + 5] = 0.0f;
        }
    }
}

extern "C" void kernel_launch(void* const* d_in, const int* in_sizes, int n_in,
                              void* d_out, int out_size, void* d_ws, size_t ws_size,
                              hipStream_t stream) {
    const float* cls_conf = (const float*)d_in[0];   // (8192, 2)
    const float* bboxes   = (const float*)d_in[1];   // (8192, 4)
    float* out = (float*)d_out;                      // (8192, 6)

    char* ws = (char*)d_ws;
    int*                partial = (int*)(ws + 0);                 // 256 KiB [i][8]
    unsigned int*       wcnt    = (unsigned int*)(ws + 262144);   //  18 KiB (4608)
    unsigned long long* validw  = (unsigned long long*)(ws + 282624); // 1 KiB
    unsigned int*       wslot   = (unsigned int*)(ws + 286720);   // 2.25 MiB (4608*128)
    (void)ws_size; (void)in_sizes; (void)n_in; (void)out_size;

    stageA<<<NRBLK + NPTILE, NTHR, 0, stream>>>(cls_conf, bboxes, partial, validw, wcnt, wslot);
    stageB<<<1, NTHR, 0, stream>>>(cls_conf, bboxes, partial, validw, wcnt, wslot, out);
}